// Round 13
// baseline (169.378 us; speedup 1.0000x reference)
//
#include <hip/hip_runtime.h>
#include <hip/hip_fp16.h>

#define N_NODES 50000
#define N_EDGES 800000
#define IN_CH   256
#define HID     32
#define HEADS1  4
#define C1      128      // HEADS1*HID
#define OUT_CH  64
#define NEG     0.2f
#define INVLN2  1.4426950408889634f
#define BSHIFT  10
#define NBKT    49                        // ceil(50000/1024)
#define BCAP    17664                     // mean 16327 + ~10 sigma

typedef _Float16 h8 __attribute__((ext_vector_type(8)));
typedef float f32x4 __attribute__((ext_vector_type(4)));

// ============ weight prep: fp16 transposed copies + bucket-cursor init ============
__global__ void k_prep(const float* __restrict__ W1, const float* __restrict__ W2,
                       _Float16* __restrict__ Wt1, _Float16* __restrict__ Wt2,
                       int* __restrict__ bcur) {
    int t = blockIdx.x * 256 + threadIdx.x;
    if (blockIdx.x == 0 && threadIdx.x < NBKT) bcur[threadIdx.x] = threadIdx.x * BCAP;
    if (t < C1 * IN_CH) {            // Wt1[c][k], c<128, k<256
        int c = t >> 8, k = t & 255;
        Wt1[t] = (_Float16)W1[(size_t)k * C1 + c];
    }
    if (t < OUT_CH * C1) {           // Wt2[c][k], c<64, k<128
        int c = t >> 7, k = t & 127;
        Wt2[t] = (_Float16)W2[(size_t)k * OUT_CH + c];
    }
}

// ====== MFMA GEMM layer1 + fused coef1 (scaled by 1/ln2 for exp2 in aggr) ======
__global__ __launch_bounds__(256) void gemm1_mfma(const float* __restrict__ X,
                                                  const _Float16* __restrict__ Wt1,
                                                  const float* __restrict__ a_s1,
                                                  const float* __restrict__ a_d1,
                                                  __half* __restrict__ H,
                                                  float* __restrict__ as_n,
                                                  float* __restrict__ ad_n) {
    __shared__ _Float16 As[64 * 40];
    __shared__ _Float16 Bt[128 * 40];
    const int tid = threadIdx.x;
    const int w = tid >> 6, lane = tid & 63;
    const int row0 = blockIdx.x * 64;
    const int lr = lane & 15, lk = (lane >> 4) * 8;
    f32x4 acc[8];
#pragma unroll
    for (int n = 0; n < 8; ++n) acc[n] = (f32x4){0.f, 0.f, 0.f, 0.f};

    for (int kk = 0; kk < IN_CH; kk += 32) {
        {   // stage A: 64x32 f32 -> fp16
            int ar = tid >> 2, aks = (tid & 3) * 8;
            int gr = row0 + ar;
            float4 v0 = make_float4(0.f, 0.f, 0.f, 0.f), v1 = v0;
            if (gr < N_NODES) {
                v0 = *(const float4*)(X + (size_t)gr * IN_CH + kk + aks);
                v1 = *(const float4*)(X + (size_t)gr * IN_CH + kk + aks + 4);
            }
            h8 hv;
            hv[0] = (_Float16)v0.x; hv[1] = (_Float16)v0.y;
            hv[2] = (_Float16)v0.z; hv[3] = (_Float16)v0.w;
            hv[4] = (_Float16)v1.x; hv[5] = (_Float16)v1.y;
            hv[6] = (_Float16)v1.z; hv[7] = (_Float16)v1.w;
            *(h8*)(&As[ar * 40 + aks]) = hv;
        }
        {   // stage B chunk from Wt1 (fp16, pre-transposed): vector copies
            int c = tid >> 1, q = tid & 1;
            const h8* wp = (const h8*)(Wt1 + (size_t)c * IN_CH + kk + q * 16);
            *(h8*)(&Bt[c * 40 + q * 16]) = wp[0];
            *(h8*)(&Bt[c * 40 + q * 16 + 8]) = wp[1];
        }
        __syncthreads();
        h8 a = *(const h8*)(&As[(w * 16 + lr) * 40 + lk]);
#pragma unroll
        for (int n = 0; n < 8; ++n) {
            h8 b = *(const h8*)(&Bt[(n * 16 + lr) * 40 + lk]);
            acc[n] = __builtin_amdgcn_mfma_f32_16x16x32_f16(a, b, acc[n], 0, 0, 0);
        }
        __syncthreads();
    }
    // C write (fp16)
#pragma unroll
    for (int n = 0; n < 8; ++n)
#pragma unroll
        for (int j = 0; j < 4; ++j) {
            int gr = row0 + w * 16 + (lane >> 4) * 4 + j;
            if (gr < N_NODES) H[(size_t)gr * C1 + n * 16 + lr] = __float2half(acc[n][j]);
        }
    // fused coef1 (x INVLN2): head h covers tiles n=2h (c'=lr), 2h+1 (c'=16+lr)
    float sa0[4], sa1[4], da0[4], da1[4];
#pragma unroll
    for (int h = 0; h < 4; ++h) {
        sa0[h] = a_s1[h * 32 + lr] * INVLN2;
        sa1[h] = a_s1[h * 32 + 16 + lr] * INVLN2;
        da0[h] = a_d1[h * 32 + lr] * INVLN2;
        da1[h] = a_d1[h * 32 + 16 + lr] * INVLN2;
    }
#pragma unroll
    for (int j = 0; j < 4; ++j) {
        float sv[4], dv[4];
#pragma unroll
        for (int h = 0; h < 4; ++h) {
            sv[h] = fmaf(acc[2 * h][j], sa0[h], acc[2 * h + 1][j] * sa1[h]);
            dv[h] = fmaf(acc[2 * h][j], da0[h], acc[2 * h + 1][j] * da1[h]);
        }
#pragma unroll
        for (int m = 1; m <= 8; m <<= 1)
#pragma unroll
            for (int h = 0; h < 4; ++h) {
                sv[h] += __shfl_xor(sv[h], m);
                dv[h] += __shfl_xor(dv[h], m);
            }
        int gr = row0 + w * 16 + (lane >> 4) * 4 + j;
        if (lr == 0 && gr < N_NODES) {
#pragma unroll
            for (int h = 0; h < 4; ++h) {
                as_n[gr * 4 + h] = sv[h];
                ad_n[gr * 4 + h] = dv[h];
            }
        }
    }
}

// ====== MFMA GEMM layer2 + fused coef2 (x INVLN2) ======
__global__ __launch_bounds__(256) void gemm2_mfma(const __half* __restrict__ A,
                                                  const _Float16* __restrict__ Wt2,
                                                  const float* __restrict__ a_s2,
                                                  const float* __restrict__ a_d2,
                                                  __half* __restrict__ H,
                                                  float* __restrict__ as_n,
                                                  float* __restrict__ ad_n) {
    __shared__ _Float16 Bt[64 * 136];
    const int tid = threadIdx.x;
    const int w = tid >> 6, lane = tid & 63;
    const int row0 = blockIdx.x * 64;
    const int lr = lane & 15, lk = (lane >> 4) * 8;
    {
        int c = tid >> 2, q = tid & 3;
        const h8* wp = (const h8*)(Wt2 + (size_t)c * C1 + q * 32);
#pragma unroll
        for (int j = 0; j < 4; ++j)
            *(h8*)(&Bt[c * 136 + q * 32 + j * 8]) = wp[j];
    }
    __syncthreads();
    f32x4 acc[4];
#pragma unroll
    for (int n = 0; n < 4; ++n) acc[n] = (f32x4){0.f, 0.f, 0.f, 0.f};
    int grow = row0 + w * 16 + lr;
    grow = grow < N_NODES ? grow : N_NODES - 1;
    const _Float16* Ah = (const _Float16*)A;
#pragma unroll
    for (int kk = 0; kk < C1; kk += 32) {
        h8 a = *(const h8*)(Ah + (size_t)grow * C1 + kk + lk);
#pragma unroll
        for (int n = 0; n < 4; ++n) {
            h8 b = *(const h8*)(&Bt[(n * 16 + lr) * 136 + kk + lk]);
            acc[n] = __builtin_amdgcn_mfma_f32_16x16x32_f16(a, b, acc[n], 0, 0, 0);
        }
    }
#pragma unroll
    for (int n = 0; n < 4; ++n)
#pragma unroll
        for (int j = 0; j < 4; ++j) {
            int gr = row0 + w * 16 + (lane >> 4) * 4 + j;
            if (gr < N_NODES) H[(size_t)gr * OUT_CH + n * 16 + lr] = __float2half(acc[n][j]);
        }
    // fused coef2 (1 head, 64 cols, x INVLN2): col = n*16+lr
    float sa[4], da[4];
#pragma unroll
    for (int n = 0; n < 4; ++n) {
        sa[n] = a_s2[n * 16 + lr] * INVLN2;
        da[n] = a_d2[n * 16 + lr] * INVLN2;
    }
#pragma unroll
    for (int j = 0; j < 4; ++j) {
        float sv = 0.f, dv = 0.f;
#pragma unroll
        for (int n = 0; n < 4; ++n) {
            sv = fmaf(acc[n][j], sa[n], sv);
            dv = fmaf(acc[n][j], da[n], dv);
        }
#pragma unroll
        for (int m = 1; m <= 8; m <<= 1) {
            sv += __shfl_xor(sv, m);
            dv += __shfl_xor(dv, m);
        }
        int gr = row0 + w * 16 + (lane >> 4) * 4 + j;
        if (lr == 0 && gr < N_NODES) {
            as_n[gr] = sv;
            ad_n[gr] = dv;
        }
    }
}

// ================= CSR build (bucketed, packed-int pairs) =================
__global__ __launch_bounds__(256) void k_bucket(const int* __restrict__ src,
                                                const int* __restrict__ dst,
                                                int* __restrict__ bcur,
                                                int* __restrict__ pairs) {
    __shared__ int cnt[NBKT];
    __shared__ int base[NBKT];
    const int t = threadIdx.x;
    if (t < NBKT) cnt[t] = 0;
    __syncthreads();
    const int e0 = blockIdx.x * 2048;
    int s[8], d[8], r[8];
#pragma unroll
    for (int k = 0; k < 8; ++k) {
        int e = e0 + t + k * 256;
        bool v = e < N_EDGES;
        s[k] = v ? src[e] : 0;
        d[k] = v ? dst[e] : -1;
        r[k] = v ? atomicAdd(&cnt[d[k] >> BSHIFT], 1) : 0;
    }
    __syncthreads();
    if (t < NBKT) base[t] = atomicAdd(&bcur[t], cnt[t]);
    __syncthreads();
#pragma unroll
    for (int k = 0; k < 8; ++k) {
        if (d[k] >= 0) {
            int bin = d[k] >> BSHIFT;
            int pos = base[bin] + r[k];
            if (pos < (bin + 1) * BCAP)      // overflow guard (10-sigma margin)
                pairs[pos] = ((d[k] & 1023) << 16) | s[k];   // src<50000<2^16
        }
    }
}

// phase B: per-bucket histogram -> LDS scan -> LDS-cursor scatter; emits estart/eend.
__global__ __launch_bounds__(256) void k_csr(const int* __restrict__ pairs,
                                             const int* __restrict__ bcur,
                                             int* __restrict__ estart,
                                             int* __restrict__ eend,
                                             int* __restrict__ esrc) {
    __shared__ int hist[1024];
    __shared__ int cur[1024];
    __shared__ int s[256];
    const int b = blockIdx.x;
    const int t = threadIdx.x;
#pragma unroll
    for (int k = t; k < 1024; k += 256) hist[k] = 0;
    __syncthreads();
    int cnt = bcur[b] - b * BCAP;
    if (cnt > BCAP) cnt = BCAP;
    const int* p = pairs + (size_t)b * BCAP;
    for (int i = t; i < cnt; i += 256)
        atomicAdd(&hist[p[i] >> 16], 1);
    __syncthreads();
    int h0 = hist[4 * t], h1 = hist[4 * t + 1], h2 = hist[4 * t + 2], h3 = hist[4 * t + 3];
    int sum = h0 + h1 + h2 + h3;
    s[t] = sum;
    __syncthreads();
#pragma unroll
    for (int o = 1; o < 256; o <<= 1) {
        int v = (t >= o) ? s[t - o] : 0;
        __syncthreads();
        s[t] += v;
        __syncthreads();
    }
    int excl = s[t] - sum;
    int gbase = b * BCAP + excl;
    cur[4 * t]     = gbase;
    cur[4 * t + 1] = gbase + h0;
    cur[4 * t + 2] = gbase + h0 + h1;
    cur[4 * t + 3] = gbase + h0 + h1 + h2;
    const int nbase = b << BSHIFT;
#pragma unroll
    for (int i = 0; i < 4; ++i) {
        int node = nbase + 4 * t + i;
        if (node < N_NODES) {
            int st = cur[4 * t + i];
            estart[node] = st;
            eend[node] = st + hist[4 * t + i];
        }
    }
    __syncthreads();
    for (int i = t; i < cnt; i += 256) {
        int v = p[i];
        int pos = atomicAdd(&cur[v >> 16], 1);
        esrc[pos] = v & 0xFFFF;
    }
}

// ====== aggr1: wave per node, 8-LANE group per edge (16 ch/lane = 2x h8), 2 slots ======
// 16 edges in flight per wave, per-edge scalar cost halved vs 16-lane quarters.
// Each lane's 16 channels stay within one head's 32-block: head = li>>1.
// All __shfl unconditional; padding slots -> weight 0 with clamped source lane.
__global__ __launch_bounds__(256) void gat_aggr1_csr(const int* __restrict__ estart,
                                                     const int* __restrict__ eend,
                                                     const int* __restrict__ esrc,
                                                     const float* __restrict__ as1,
                                                     const float* __restrict__ ad1,
                                                     const __half* __restrict__ h1,
                                                     const float* __restrict__ b1,
                                                     __half* __restrict__ hrelu) {
    int n = blockIdx.x * 4 + (threadIdx.x >> 6);
    if (n >= N_NODES) return;
    const int lane = threadIdx.x & 63;
    const int q = lane >> 3, li = lane & 7;
    const int head = li >> 1;
    const int c0 = li * 16;
    const int base = estart[n];
    const int end = eend[n];
    const float ad = ad1[n * 4 + head];
    const _Float16* __restrict__ H = (const _Float16*)h1;
    float den0 = 0.f, den1 = 0.f;
    float accA0[8], accB0[8], accA1[8], accB1[8];
#pragma unroll
    for (int k = 0; k < 8; ++k) { accA0[k] = 0.f; accB0[k] = 0.f; accA1[k] = 0.f; accB1[k] = 0.f; }

    for (int b0 = base; b0 < end; b0 += 64) {
        int cnt = end - b0; if (cnt > 64) cnt = 64;
        int myidx = (lane < cnt) ? esrc[b0 + lane] : 0;
        for (int it = 0; it < cnt; it += 16) {
            int j0 = it + q * 2, j1 = j0 + 1;
            bool p0 = j0 < cnt, p1 = j1 < cnt;
            int s0 = __shfl(myidx, p0 ? j0 : 0);
            int s1 = __shfl(myidx, p1 ? j1 : 0);
            float x0 = as1[s0 * 4 + head] + ad;
            x0 = x0 > 0.f ? x0 : NEG * x0;
            float w0 = p0 ? exp2f(x0) : 0.f;     // coefs pre-scaled by 1/ln2
            float x1 = as1[s1 * 4 + head] + ad;
            x1 = x1 > 0.f ? x1 : NEG * x1;
            float w1 = p1 ? exp2f(x1) : 0.f;
            h8 a0 = *(const h8*)(H + (size_t)s0 * C1 + c0);
            h8 b0v = *(const h8*)(H + (size_t)s0 * C1 + c0 + 8);
            h8 a1 = *(const h8*)(H + (size_t)s1 * C1 + c0);
            h8 b1v = *(const h8*)(H + (size_t)s1 * C1 + c0 + 8);
            den0 += w0;
            den1 += w1;
#pragma unroll
            for (int k = 0; k < 8; ++k) {
                accA0[k] = fmaf((float)a0[k], w0, accA0[k]);
                accB0[k] = fmaf((float)b0v[k], w0, accB0[k]);
                accA1[k] = fmaf((float)a1[k], w1, accA1[k]);
                accB1[k] = fmaf((float)b1v[k], w1, accB1[k]);
            }
        }
    }
    float den = den0 + den1;
    float rA[8], rB[8];
#pragma unroll
    for (int k = 0; k < 8; ++k) { rA[k] = accA0[k] + accA1[k]; rB[k] = accB0[k] + accB1[k]; }
    den += __shfl_xor(den, 8);
    den += __shfl_xor(den, 16);
    den += __shfl_xor(den, 32);
#pragma unroll
    for (int k = 0; k < 8; ++k) {
        rA[k] += __shfl_xor(rA[k], 8);
        rA[k] += __shfl_xor(rA[k], 16);
        rA[k] += __shfl_xor(rA[k], 32);
        rB[k] += __shfl_xor(rB[k], 8);
        rB[k] += __shfl_xor(rB[k], 16);
        rB[k] += __shfl_xor(rB[k], 32);
    }
    if (q == 0) {
        float inv = 1.f / (den + 1e-16f);
        float4 bb0 = *(const float4*)(b1 + c0);
        float4 bb1 = *(const float4*)(b1 + c0 + 4);
        float4 bb2 = *(const float4*)(b1 + c0 + 8);
        float4 bb3 = *(const float4*)(b1 + c0 + 12);
        float bvA[8] = {bb0.x, bb0.y, bb0.z, bb0.w, bb1.x, bb1.y, bb1.z, bb1.w};
        float bvB[8] = {bb2.x, bb2.y, bb2.z, bb2.w, bb3.x, bb3.y, bb3.z, bb3.w};
        h8 oA, oB;
#pragma unroll
        for (int k = 0; k < 8; ++k) {
            float vA = fmaf(rA[k], inv, bvA[k]);
            float vB = fmaf(rB[k], inv, bvB[k]);
            oA[k] = (_Float16)(vA > 0.f ? vA : 0.f);
            oB[k] = (_Float16)(vB > 0.f ? vB : 0.f);
        }
        *(h8*)((_Float16*)hrelu + (size_t)n * C1 + c0) = oA;
        *(h8*)((_Float16*)hrelu + (size_t)n * C1 + c0 + 8) = oB;
    }
}

// ====== aggr2: wave per node, 8-lane group per edge (full row), 2 slots ======
__global__ __launch_bounds__(256) void gat_aggr2_csr(const int* __restrict__ estart,
                                                     const int* __restrict__ eend,
                                                     const int* __restrict__ esrc,
                                                     const float* __restrict__ as2,
                                                     const float* __restrict__ ad2,
                                                     const __half* __restrict__ h2,
                                                     const float* __restrict__ b2,
                                                     float* __restrict__ out) {
    int n = blockIdx.x * 4 + (threadIdx.x >> 6);
    if (n >= N_NODES) return;
    const int lane = threadIdx.x & 63;
    const int q = lane >> 3, li = lane & 7;
    const int c0 = li * 8;
    const int base = estart[n];
    const int end = eend[n];
    const float ad = ad2[n];
    const _Float16* __restrict__ H = (const _Float16*)h2;
    float den0 = 0.f, den1 = 0.f;
    float acc0[8], acc1[8];
#pragma unroll
    for (int k = 0; k < 8; ++k) { acc0[k] = 0.f; acc1[k] = 0.f; }

    for (int b0 = base; b0 < end; b0 += 64) {
        int cnt = end - b0; if (cnt > 64) cnt = 64;
        int myidx = (lane < cnt) ? esrc[b0 + lane] : 0;
        for (int it = 0; it < cnt; it += 16) {
            int j0 = it + q * 2, j1 = j0 + 1;
            bool p0 = j0 < cnt, p1 = j1 < cnt;
            int s0 = __shfl(myidx, p0 ? j0 : 0);
            int s1 = __shfl(myidx, p1 ? j1 : 0);
            float x0 = as2[s0] + ad;
            x0 = x0 > 0.f ? x0 : NEG * x0;
            float w0 = p0 ? exp2f(x0) : 0.f;
            float x1 = as2[s1] + ad;
            x1 = x1 > 0.f ? x1 : NEG * x1;
            float w1 = p1 ? exp2f(x1) : 0.f;
            h8 hv0 = *(const h8*)(H + (size_t)s0 * OUT_CH + c0);
            h8 hv1 = *(const h8*)(H + (size_t)s1 * OUT_CH + c0);
            den0 += w0;
            den1 += w1;
#pragma unroll
            for (int k = 0; k < 8; ++k) {
                acc0[k] = fmaf((float)hv0[k], w0, acc0[k]);
                acc1[k] = fmaf((float)hv1[k], w1, acc1[k]);
            }
        }
    }
    float den = den0 + den1;
    float r[8];
#pragma unroll
    for (int k = 0; k < 8; ++k) r[k] = acc0[k] + acc1[k];
    den += __shfl_xor(den, 8);
    den += __shfl_xor(den, 16);
    den += __shfl_xor(den, 32);
#pragma unroll
    for (int k = 0; k < 8; ++k) {
        r[k] += __shfl_xor(r[k], 8);
        r[k] += __shfl_xor(r[k], 16);
        r[k] += __shfl_xor(r[k], 32);
    }
    if (q == 0) {
        float4 bb0 = *(const float4*)(b2 + c0);
        float4 bb1 = *(const float4*)(b2 + c0 + 4);
        float inv = 1.f / (den + 1e-16f);
        float4 o0, o1;
        o0.x = fmaf(r[0], inv, bb0.x);
        o0.y = fmaf(r[1], inv, bb0.y);
        o0.z = fmaf(r[2], inv, bb0.z);
        o0.w = fmaf(r[3], inv, bb0.w);
        o1.x = fmaf(r[4], inv, bb1.x);
        o1.y = fmaf(r[5], inv, bb1.y);
        o1.z = fmaf(r[6], inv, bb1.z);
        o1.w = fmaf(r[7], inv, bb1.w);
        *(float4*)(out + (size_t)n * OUT_CH + c0) = o0;
        *(float4*)(out + (size_t)n * OUT_CH + c0 + 4) = o1;
    }
}

extern "C" void kernel_launch(void* const* d_in, const int* in_sizes, int n_in,
                              void* d_out, int out_size, void* d_ws, size_t ws_size,
                              hipStream_t stream) {
    const float* x      = (const float*)d_in[0];
    const int*   ei     = (const int*)d_in[1];
    const float* W1     = (const float*)d_in[2];
    const float* a_src1 = (const float*)d_in[3];
    const float* a_dst1 = (const float*)d_in[4];
    const float* b1     = (const float*)d_in[5];
    const float* W2     = (const float*)d_in[6];
    const float* a_src2 = (const float*)d_in[7];
    const float* a_dst2 = (const float*)d_in[8];
    const float* b2     = (const float*)d_in[9];
    float* out = (float*)d_out;

    const int* src = ei;
    const int* dst = ei + N_EDGES;

    char* w = (char*)d_ws;
    auto carve = [&](size_t bytes) {
        char* p = w;
        w += (bytes + 255) & ~(size_t)255;
        return p;
    };
    __half*   h1     = (__half*)carve((size_t)N_NODES * C1 * 2);   // phase2: h2 aliases
    __half*   hrelu  = (__half*)carve((size_t)N_NODES * C1 * 2);
    float*    as1    = (float*)carve((size_t)N_NODES * 4 * 4);     // phase2: as2
    float*    ad1    = (float*)carve((size_t)N_NODES * 4 * 4);     // phase2: ad2
    int*      estart = (int*)carve((size_t)N_NODES * 4);
    int*      eend   = (int*)carve((size_t)N_NODES * 4);
    int*      esrc   = (int*)carve((size_t)NBKT * BCAP * 4);
    int*      bcur   = (int*)carve((size_t)NBKT * 4);
    int*      pairs  = (int*)carve((size_t)NBKT * BCAP * 4);
    _Float16* Wt1    = (_Float16*)carve((size_t)C1 * IN_CH * 2);
    _Float16* Wt2    = (_Float16*)carve((size_t)OUT_CH * C1 * 2);

    __half* h2  = h1;
    float*  as2 = as1;
    float*  ad2 = ad1;

    // ---- CSR build (3 kernels; shared by both layers) ----
    k_prep<<<(C1 * IN_CH + 255) / 256, 256, 0, stream>>>(W1, W2, Wt1, Wt2, bcur);
    k_bucket<<<(N_EDGES + 2047) / 2048, 256, 0, stream>>>(src, dst, bcur, pairs);
    k_csr<<<NBKT, 256, 0, stream>>>(pairs, bcur, estart, eend, esrc);

    // ---- layer 1 ----
    gemm1_mfma<<<(N_NODES + 63) / 64, 256, 0, stream>>>(x, Wt1, a_src1, a_dst1, h1, as1, ad1);
    gat_aggr1_csr<<<(N_NODES + 3) / 4, 256, 0, stream>>>(estart, eend, esrc, as1, ad1, h1, b1, hrelu);

    // ---- layer 2 ----
    gemm2_mfma<<<(N_NODES + 63) / 64, 256, 0, stream>>>(hrelu, Wt2, a_src2, a_dst2, h2, as2, ad2);
    gat_aggr2_csr<<<(N_NODES + 3) / 4, 256, 0, stream>>>(estart, eend, esrc, as2, ad2, h2, b2, out);

    (void)in_sizes; (void)n_in; (void)out_size; (void)ws_size;
}

// Round 14
// 156.300 us; speedup vs baseline: 1.0837x; 1.0837x over previous
//
#include <hip/hip_runtime.h>
#include <hip/hip_fp16.h>

#define N_NODES 50000
#define N_EDGES 800000
#define IN_CH   256
#define HID     32
#define HEADS1  4
#define C1      128      // HEADS1*HID
#define OUT_CH  64
#define NEG     0.2f
#define INVLN2  1.4426950408889634f
#define BSHIFT  10
#define NBKT    49                        // ceil(50000/1024)
#define BCAP    17664                     // mean 16327 + ~10 sigma
#define N1E     144                       // 128 h-cols + 4 as + 4 ad + 8 pad
#define N2E     80                        // 64 h-cols + as + ad + 14 pad

typedef _Float16 h8 __attribute__((ext_vector_type(8)));
typedef float f32x4 __attribute__((ext_vector_type(4)));

// ===== weight prep: fp16 transposed W + attention-vector columns + bcur init =====
// Coef fusion: as_n = X @ Va with Va[k][h] = sum_c W1[k][32h+c]*a_s[h][c]*INVLN2.
// Va/Vd become extra GEMM columns -> coef epilogue is just a C-tile write.
__global__ void k_prep(const float* __restrict__ W1, const float* __restrict__ W2,
                       const float* __restrict__ a_s1, const float* __restrict__ a_d1,
                       const float* __restrict__ a_s2, const float* __restrict__ a_d2,
                       _Float16* __restrict__ Wt1e, _Float16* __restrict__ Wt2e,
                       int* __restrict__ bcur) {
    int t = blockIdx.x * 256 + threadIdx.x;
    if (blockIdx.x == 0 && threadIdx.x < NBKT) bcur[threadIdx.x] = threadIdx.x * BCAP;
    if (t < 32768) {                       // Wt1e cols 0..127 (transpose W1)
        int c = t >> 8, k = t & 255;
        Wt1e[(size_t)c * 256 + k] = (_Float16)W1[(size_t)k * C1 + c];
    } else if (t < 34816) {                // cols 128..135: Va1 (h<4), Vd1
        int i = t - 32768;
        int k = i & 255, h = (i >> 8) & 3, which = i >> 10;
        const float* av = which ? a_d1 : a_s1;
        float s = 0.f;
        for (int c = 0; c < 32; ++c)
            s = fmaf(W1[(size_t)k * C1 + h * 32 + c], av[h * 32 + c], s);
        Wt1e[(size_t)(128 + which * 4 + h) * 256 + k] = (_Float16)(s * INVLN2);
    } else if (t < 36864) {                // zero pad cols 136..143
        int i = t - 34816;
        int k = i & 255, c = 136 + (i >> 8);
        Wt1e[(size_t)c * 256 + k] = (_Float16)0.f;
    } else if (t < 45056) {                // Wt2e cols 0..63 (transpose W2)
        int i = t - 36864;
        int c = i >> 7, k = i & 127;
        Wt2e[(size_t)c * 128 + k] = (_Float16)W2[(size_t)k * OUT_CH + c];
    } else if (t < 45312) {                // cols 64,65: Va2, Vd2
        int i = t - 45056;
        int k = i & 127, which = i >> 7;
        const float* av = which ? a_d2 : a_s2;
        float s = 0.f;
        for (int c = 0; c < 64; ++c)
            s = fmaf(W2[(size_t)k * OUT_CH + c], av[c], s);
        Wt2e[(size_t)(64 + which) * 128 + k] = (_Float16)(s * INVLN2);
    } else if (t < 47104) {                // zero pad cols 66..79
        int i = t - 45312;
        int k = i & 127, c = 66 + (i >> 7);
        Wt2e[(size_t)c * 128 + k] = (_Float16)0.f;
    }
}

// ====== MFMA GEMM layer1: [h1 | as | ad] = X @ Wt1e (9 tiles, shuffle-free) ======
__global__ __launch_bounds__(256) void gemm1_mfma(const float* __restrict__ X,
                                                  const _Float16* __restrict__ Wt1e,
                                                  __half* __restrict__ H,
                                                  float* __restrict__ as_n,
                                                  float* __restrict__ ad_n) {
    __shared__ _Float16 As[64 * 40];
    __shared__ _Float16 Bt[N1E * 40];
    const int tid = threadIdx.x;
    const int w = tid >> 6, lane = tid & 63;
    const int row0 = blockIdx.x * 64;
    const int lr = lane & 15, lk = (lane >> 4) * 8;
    f32x4 acc[9];
#pragma unroll
    for (int n = 0; n < 9; ++n) acc[n] = (f32x4){0.f, 0.f, 0.f, 0.f};

    for (int kk = 0; kk < IN_CH; kk += 32) {
        {   // stage A: 64x32 f32 -> fp16
            int ar = tid >> 2, aks = (tid & 3) * 8;
            int gr = row0 + ar;
            float4 v0 = make_float4(0.f, 0.f, 0.f, 0.f), v1 = v0;
            if (gr < N_NODES) {
                v0 = *(const float4*)(X + (size_t)gr * IN_CH + kk + aks);
                v1 = *(const float4*)(X + (size_t)gr * IN_CH + kk + aks + 4);
            }
            h8 hv;
            hv[0] = (_Float16)v0.x; hv[1] = (_Float16)v0.y;
            hv[2] = (_Float16)v0.z; hv[3] = (_Float16)v0.w;
            hv[4] = (_Float16)v1.x; hv[5] = (_Float16)v1.y;
            hv[6] = (_Float16)v1.z; hv[7] = (_Float16)v1.w;
            *(h8*)(&As[ar * 40 + aks]) = hv;
        }
        // stage B: one thread per col (tid<144), 4x h8 vector copies
        if (tid < N1E) {
            const h8* wp = (const h8*)(Wt1e + (size_t)tid * IN_CH + kk);
            *(h8*)(&Bt[tid * 40 + 0])  = wp[0];
            *(h8*)(&Bt[tid * 40 + 8])  = wp[1];
            *(h8*)(&Bt[tid * 40 + 16]) = wp[2];
            *(h8*)(&Bt[tid * 40 + 24]) = wp[3];
        }
        __syncthreads();
        h8 a = *(const h8*)(&As[(w * 16 + lr) * 40 + lk]);
#pragma unroll
        for (int n = 0; n < 9; ++n) {
            h8 b = *(const h8*)(&Bt[(n * 16 + lr) * 40 + lk]);
            acc[n] = __builtin_amdgcn_mfma_f32_16x16x32_f16(a, b, acc[n], 0, 0, 0);
        }
        __syncthreads();
    }
    // C write (fp16), tiles 0..7
#pragma unroll
    for (int n = 0; n < 8; ++n)
#pragma unroll
        for (int j = 0; j < 4; ++j) {
            int gr = row0 + w * 16 + (lane >> 4) * 4 + j;
            if (gr < N_NODES) H[(size_t)gr * C1 + n * 16 + lr] = __float2half(acc[n][j]);
        }
    // tile 8 = coefs: col 128+lr -> lr<4: as[head=lr], lr in [4,8): ad[head=lr-4]
#pragma unroll
    for (int j = 0; j < 4; ++j) {
        int gr = row0 + w * 16 + (lane >> 4) * 4 + j;
        if (gr < N_NODES) {
            if (lr < 4) as_n[gr * 4 + lr] = acc[8][j];
            else if (lr < 8) ad_n[gr * 4 + (lr - 4)] = acc[8][j];
        }
    }
}

// ====== MFMA GEMM layer2: [h2 | as2 | ad2] = hrelu @ Wt2e (5 tiles) ======
__global__ __launch_bounds__(256) void gemm2_mfma(const __half* __restrict__ A,
                                                  const _Float16* __restrict__ Wt2e,
                                                  __half* __restrict__ H,
                                                  float* __restrict__ as_n,
                                                  float* __restrict__ ad_n) {
    __shared__ _Float16 Bt[N2E * 136];
    const int tid = threadIdx.x;
    const int w = tid >> 6, lane = tid & 63;
    const int row0 = blockIdx.x * 64;
    const int lr = lane & 15, lk = (lane >> 4) * 8;
    if (tid < 160) {
        int c = tid >> 1, q = tid & 1;
        const h8* wp = (const h8*)(Wt2e + (size_t)c * C1 + q * 64);
#pragma unroll
        for (int j = 0; j < 8; ++j)
            *(h8*)(&Bt[c * 136 + q * 64 + j * 8]) = wp[j];
    }
    __syncthreads();
    f32x4 acc[5];
#pragma unroll
    for (int n = 0; n < 5; ++n) acc[n] = (f32x4){0.f, 0.f, 0.f, 0.f};
    int grow = row0 + w * 16 + lr;
    grow = grow < N_NODES ? grow : N_NODES - 1;
    const _Float16* Ah = (const _Float16*)A;
#pragma unroll
    for (int kk = 0; kk < C1; kk += 32) {
        h8 a = *(const h8*)(Ah + (size_t)grow * C1 + kk + lk);
#pragma unroll
        for (int n = 0; n < 5; ++n) {
            h8 b = *(const h8*)(&Bt[(n * 16 + lr) * 136 + kk + lk]);
            acc[n] = __builtin_amdgcn_mfma_f32_16x16x32_f16(a, b, acc[n], 0, 0, 0);
        }
    }
#pragma unroll
    for (int n = 0; n < 4; ++n)
#pragma unroll
        for (int j = 0; j < 4; ++j) {
            int gr = row0 + w * 16 + (lane >> 4) * 4 + j;
            if (gr < N_NODES) H[(size_t)gr * OUT_CH + n * 16 + lr] = __float2half(acc[n][j]);
        }
    // tile 4 = coefs: col 64+lr -> lr==0: as2, lr==1: ad2
#pragma unroll
    for (int j = 0; j < 4; ++j) {
        int gr = row0 + w * 16 + (lane >> 4) * 4 + j;
        if (gr < N_NODES) {
            if (lr == 0) as_n[gr] = acc[4][j];
            else if (lr == 1) ad_n[gr] = acc[4][j];
        }
    }
}

// ================= CSR build (bucketed, packed-int pairs) =================
__global__ __launch_bounds__(256) void k_bucket(const int* __restrict__ src,
                                                const int* __restrict__ dst,
                                                int* __restrict__ bcur,
                                                int* __restrict__ pairs) {
    __shared__ int cnt[NBKT];
    __shared__ int base[NBKT];
    const int t = threadIdx.x;
    if (t < NBKT) cnt[t] = 0;
    __syncthreads();
    const int e0 = blockIdx.x * 2048;
    int s[8], d[8], r[8];
#pragma unroll
    for (int k = 0; k < 8; ++k) {
        int e = e0 + t + k * 256;
        bool v = e < N_EDGES;
        s[k] = v ? src[e] : 0;
        d[k] = v ? dst[e] : -1;
        r[k] = v ? atomicAdd(&cnt[d[k] >> BSHIFT], 1) : 0;
    }
    __syncthreads();
    if (t < NBKT) base[t] = atomicAdd(&bcur[t], cnt[t]);
    __syncthreads();
#pragma unroll
    for (int k = 0; k < 8; ++k) {
        if (d[k] >= 0) {
            int bin = d[k] >> BSHIFT;
            int pos = base[bin] + r[k];
            if (pos < (bin + 1) * BCAP)      // overflow guard (10-sigma margin)
                pairs[pos] = ((d[k] & 1023) << 16) | s[k];   // src<50000<2^16
        }
    }
}

// phase B: per-bucket histogram -> LDS scan -> LDS-cursor scatter; emits estart/eend.
__global__ __launch_bounds__(256) void k_csr(const int* __restrict__ pairs,
                                             const int* __restrict__ bcur,
                                             int* __restrict__ estart,
                                             int* __restrict__ eend,
                                             int* __restrict__ esrc) {
    __shared__ int hist[1024];
    __shared__ int cur[1024];
    __shared__ int s[256];
    const int b = blockIdx.x;
    const int t = threadIdx.x;
#pragma unroll
    for (int k = t; k < 1024; k += 256) hist[k] = 0;
    __syncthreads();
    int cnt = bcur[b] - b * BCAP;
    if (cnt > BCAP) cnt = BCAP;
    const int* p = pairs + (size_t)b * BCAP;
    for (int i = t; i < cnt; i += 256)
        atomicAdd(&hist[p[i] >> 16], 1);
    __syncthreads();
    int h0 = hist[4 * t], h1 = hist[4 * t + 1], h2 = hist[4 * t + 2], h3 = hist[4 * t + 3];
    int sum = h0 + h1 + h2 + h3;
    s[t] = sum;
    __syncthreads();
#pragma unroll
    for (int o = 1; o < 256; o <<= 1) {
        int v = (t >= o) ? s[t - o] : 0;
        __syncthreads();
        s[t] += v;
        __syncthreads();
    }
    int excl = s[t] - sum;
    int gbase = b * BCAP + excl;
    cur[4 * t]     = gbase;
    cur[4 * t + 1] = gbase + h0;
    cur[4 * t + 2] = gbase + h0 + h1;
    cur[4 * t + 3] = gbase + h0 + h1 + h2;
    const int nbase = b << BSHIFT;
#pragma unroll
    for (int i = 0; i < 4; ++i) {
        int node = nbase + 4 * t + i;
        if (node < N_NODES) {
            int st = cur[4 * t + i];
            estart[node] = st;
            eend[node] = st + hist[4 * t + i];
        }
    }
    __syncthreads();
    for (int i = t; i < cnt; i += 256) {
        int v = p[i];
        int pos = atomicAdd(&cur[v >> 16], 1);
        esrc[pos] = v & 0xFFFF;
    }
}

// ====== aggr1 (R12-best config): wave per node, 16-lane quarter, 2 slots ======
// 8 edges in flight, 28 VGPR, ~65% occupancy — measured optimum.
__global__ __launch_bounds__(256) void gat_aggr1_csr(const int* __restrict__ estart,
                                                     const int* __restrict__ eend,
                                                     const int* __restrict__ esrc,
                                                     const float* __restrict__ as1,
                                                     const float* __restrict__ ad1,
                                                     const __half* __restrict__ h1,
                                                     const float* __restrict__ b1,
                                                     __half* __restrict__ hrelu) {
    int n = blockIdx.x * 4 + (threadIdx.x >> 6);
    if (n >= N_NODES) return;
    const int lane = threadIdx.x & 63;
    const int q = lane >> 4, li = lane & 15;
    const int head = li >> 2;
    const int c0 = li * 8;
    const int base = estart[n];
    const int end = eend[n];
    const float ad = ad1[n * 4 + head];
    const _Float16* __restrict__ H = (const _Float16*)h1;
    float den0 = 0.f, den1 = 0.f;
    float acc0[8], acc1[8];
#pragma unroll
    for (int k = 0; k < 8; ++k) { acc0[k] = 0.f; acc1[k] = 0.f; }

    for (int b0 = base; b0 < end; b0 += 64) {
        int cnt = end - b0; if (cnt > 64) cnt = 64;
        int myidx = (lane < cnt) ? esrc[b0 + lane] : 0;
        for (int it = 0; it < cnt; it += 8) {
            int j0 = it + q * 2, j1 = j0 + 1;
            bool p0 = j0 < cnt, p1 = j1 < cnt;
            int s0 = __shfl(myidx, p0 ? j0 : 0);
            int s1 = __shfl(myidx, p1 ? j1 : 0);
            float x0 = as1[s0 * 4 + head] + ad;
            x0 = x0 > 0.f ? x0 : NEG * x0;
            float w0 = p0 ? exp2f(x0) : 0.f;     // coefs pre-scaled by 1/ln2
            float x1 = as1[s1 * 4 + head] + ad;
            x1 = x1 > 0.f ? x1 : NEG * x1;
            float w1 = p1 ? exp2f(x1) : 0.f;
            h8 hv0 = *(const h8*)(H + (size_t)s0 * C1 + c0);
            h8 hv1 = *(const h8*)(H + (size_t)s1 * C1 + c0);
            den0 += w0;
            den1 += w1;
#pragma unroll
            for (int k = 0; k < 8; ++k) {
                acc0[k] = fmaf((float)hv0[k], w0, acc0[k]);
                acc1[k] = fmaf((float)hv1[k], w1, acc1[k]);
            }
        }
    }
    float den = den0 + den1;
    float r[8];
#pragma unroll
    for (int k = 0; k < 8; ++k) r[k] = acc0[k] + acc1[k];
    den += __shfl_xor(den, 16);
    den += __shfl_xor(den, 32);
#pragma unroll
    for (int k = 0; k < 8; ++k) {
        r[k] += __shfl_xor(r[k], 16);
        r[k] += __shfl_xor(r[k], 32);
    }
    if (q == 0) {
        float4 bb0 = *(const float4*)(b1 + c0);
        float4 bb1 = *(const float4*)(b1 + c0 + 4);
        float bv[8] = {bb0.x, bb0.y, bb0.z, bb0.w, bb1.x, bb1.y, bb1.z, bb1.w};
        float inv = 1.f / (den + 1e-16f);
        h8 o;
#pragma unroll
        for (int k = 0; k < 8; ++k) {
            float v = fmaf(r[k], inv, bv[k]);
            o[k] = (_Float16)(v > 0.f ? v : 0.f);
        }
        *(h8*)((_Float16*)hrelu + (size_t)n * C1 + c0) = o;
    }
}

// ====== aggr2 (R12 config): wave per node, 8-lane group per edge, 2 slots ======
__global__ __launch_bounds__(256) void gat_aggr2_csr(const int* __restrict__ estart,
                                                     const int* __restrict__ eend,
                                                     const int* __restrict__ esrc,
                                                     const float* __restrict__ as2,
                                                     const float* __restrict__ ad2,
                                                     const __half* __restrict__ h2,
                                                     const float* __restrict__ b2,
                                                     float* __restrict__ out) {
    int n = blockIdx.x * 4 + (threadIdx.x >> 6);
    if (n >= N_NODES) return;
    const int lane = threadIdx.x & 63;
    const int q = lane >> 3, li = lane & 7;
    const int c0 = li * 8;
    const int base = estart[n];
    const int end = eend[n];
    const float ad = ad2[n];
    const _Float16* __restrict__ H = (const _Float16*)h2;
    float den0 = 0.f, den1 = 0.f;
    float acc0[8], acc1[8];
#pragma unroll
    for (int k = 0; k < 8; ++k) { acc0[k] = 0.f; acc1[k] = 0.f; }

    for (int b0 = base; b0 < end; b0 += 64) {
        int cnt = end - b0; if (cnt > 64) cnt = 64;
        int myidx = (lane < cnt) ? esrc[b0 + lane] : 0;
        for (int it = 0; it < cnt; it += 16) {
            int j0 = it + q * 2, j1 = j0 + 1;
            bool p0 = j0 < cnt, p1 = j1 < cnt;
            int s0 = __shfl(myidx, p0 ? j0 : 0);
            int s1 = __shfl(myidx, p1 ? j1 : 0);
            float x0 = as2[s0] + ad;
            x0 = x0 > 0.f ? x0 : NEG * x0;
            float w0 = p0 ? exp2f(x0) : 0.f;
            float x1 = as2[s1] + ad;
            x1 = x1 > 0.f ? x1 : NEG * x1;
            float w1 = p1 ? exp2f(x1) : 0.f;
            h8 hv0 = *(const h8*)(H + (size_t)s0 * OUT_CH + c0);
            h8 hv1 = *(const h8*)(H + (size_t)s1 * OUT_CH + c0);
            den0 += w0;
            den1 += w1;
#pragma unroll
            for (int k = 0; k < 8; ++k) {
                acc0[k] = fmaf((float)hv0[k], w0, acc0[k]);
                acc1[k] = fmaf((float)hv1[k], w1, acc1[k]);
            }
        }
    }
    float den = den0 + den1;
    float r[8];
#pragma unroll
    for (int k = 0; k < 8; ++k) r[k] = acc0[k] + acc1[k];
    den += __shfl_xor(den, 8);
    den += __shfl_xor(den, 16);
    den += __shfl_xor(den, 32);
#pragma unroll
    for (int k = 0; k < 8; ++k) {
        r[k] += __shfl_xor(r[k], 8);
        r[k] += __shfl_xor(r[k], 16);
        r[k] += __shfl_xor(r[k], 32);
    }
    if (q == 0) {
        float4 bb0 = *(const float4*)(b2 + c0);
        float4 bb1 = *(const float4*)(b2 + c0 + 4);
        float inv = 1.f / (den + 1e-16f);
        float4 o0, o1;
        o0.x = fmaf(r[0], inv, bb0.x);
        o0.y = fmaf(r[1], inv, bb0.y);
        o0.z = fmaf(r[2], inv, bb0.z);
        o0.w = fmaf(r[3], inv, bb0.w);
        o1.x = fmaf(r[4], inv, bb1.x);
        o1.y = fmaf(r[5], inv, bb1.y);
        o1.z = fmaf(r[6], inv, bb1.z);
        o1.w = fmaf(r[7], inv, bb1.w);
        *(float4*)(out + (size_t)n * OUT_CH + c0) = o0;
        *(float4*)(out + (size_t)n * OUT_CH + c0 + 4) = o1;
    }
}

extern "C" void kernel_launch(void* const* d_in, const int* in_sizes, int n_in,
                              void* d_out, int out_size, void* d_ws, size_t ws_size,
                              hipStream_t stream) {
    const float* x      = (const float*)d_in[0];
    const int*   ei     = (const int*)d_in[1];
    const float* W1     = (const float*)d_in[2];
    const float* a_src1 = (const float*)d_in[3];
    const float* a_dst1 = (const float*)d_in[4];
    const float* b1     = (const float*)d_in[5];
    const float* W2     = (const float*)d_in[6];
    const float* a_src2 = (const float*)d_in[7];
    const float* a_dst2 = (const float*)d_in[8];
    const float* b2     = (const float*)d_in[9];
    float* out = (float*)d_out;

    const int* src = ei;
    const int* dst = ei + N_EDGES;

    char* w = (char*)d_ws;
    auto carve = [&](size_t bytes) {
        char* p = w;
        w += (bytes + 255) & ~(size_t)255;
        return p;
    };
    __half*   h1     = (__half*)carve((size_t)N_NODES * C1 * 2);   // phase2: h2 aliases
    __half*   hrelu  = (__half*)carve((size_t)N_NODES * C1 * 2);
    float*    as1    = (float*)carve((size_t)N_NODES * 4 * 4);     // phase2: as2
    float*    ad1    = (float*)carve((size_t)N_NODES * 4 * 4);     // phase2: ad2
    int*      estart = (int*)carve((size_t)N_NODES * 4);
    int*      eend   = (int*)carve((size_t)N_NODES * 4);
    int*      esrc   = (int*)carve((size_t)NBKT * BCAP * 4);
    int*      bcur   = (int*)carve((size_t)NBKT * 4);
    int*      pairs  = (int*)carve((size_t)NBKT * BCAP * 4);
    _Float16* Wt1e   = (_Float16*)carve((size_t)N1E * IN_CH * 2);
    _Float16* Wt2e   = (_Float16*)carve((size_t)N2E * C1 * 2);

    __half* h2  = h1;
    float*  as2 = as1;
    float*  ad2 = ad1;

    // ---- CSR build + weight prep (3 kernels; shared by both layers) ----
    k_prep<<<184, 256, 0, stream>>>(W1, W2, a_src1, a_dst1, a_src2, a_dst2,
                                    Wt1e, Wt2e, bcur);
    k_bucket<<<(N_EDGES + 2047) / 2048, 256, 0, stream>>>(src, dst, bcur, pairs);
    k_csr<<<NBKT, 256, 0, stream>>>(pairs, bcur, estart, eend, esrc);

    // ---- layer 1 ----
    gemm1_mfma<<<(N_NODES + 63) / 64, 256, 0, stream>>>(x, Wt1e, h1, as1, ad1);
    gat_aggr1_csr<<<(N_NODES + 3) / 4, 256, 0, stream>>>(estart, eend, esrc, as1, ad1, h1, b1, hrelu);

    // ---- layer 2 ----
    gemm2_mfma<<<(N_NODES + 63) / 64, 256, 0, stream>>>(hrelu, Wt2e, h2, as2, ad2);
    gat_aggr2_csr<<<(N_NODES + 3) / 4, 256, 0, stream>>>(estart, eend, esrc, as2, ad2, h2, b2, out);

    (void)in_sizes; (void)n_in; (void)out_size; (void)ws_size;
}

// Round 15
// 155.384 us; speedup vs baseline: 1.0901x; 1.0059x over previous
//
#include <hip/hip_runtime.h>
#include <hip/hip_fp16.h>

#define N_NODES 50000
#define N_EDGES 800000
#define IN_CH   256
#define HID     32
#define HEADS1  4
#define C1      128      // HEADS1*HID
#define OUT_CH  64
#define NEG     0.2f
#define INVLN2  1.4426950408889634f
#define BSHIFT  10
#define NBKT    49                        // ceil(50000/1024)
#define BCAP    17664                     // mean 16327 + ~10 sigma
#define N1E     144                       // 128 h-cols + 4 as + 4 ad + 8 pad
#define N2E     80                        // 64 h-cols + as + ad + 14 pad

typedef _Float16 h8 __attribute__((ext_vector_type(8)));
typedef float f32x4 __attribute__((ext_vector_type(4)));

// ===== weight prep: fp16 transposed W + attention-vector columns + bcur init =====
__global__ void k_prep(const float* __restrict__ W1, const float* __restrict__ W2,
                       const float* __restrict__ a_s1, const float* __restrict__ a_d1,
                       const float* __restrict__ a_s2, const float* __restrict__ a_d2,
                       _Float16* __restrict__ Wt1e, _Float16* __restrict__ Wt2e,
                       int* __restrict__ bcur) {
    int t = blockIdx.x * 256 + threadIdx.x;
    if (blockIdx.x == 0 && threadIdx.x < NBKT) bcur[threadIdx.x] = threadIdx.x * BCAP;
    if (t < 32768) {                       // Wt1e cols 0..127 (transpose W1)
        int c = t >> 8, k = t & 255;
        Wt1e[(size_t)c * 256 + k] = (_Float16)W1[(size_t)k * C1 + c];
    } else if (t < 34816) {                // cols 128..135: Va1 (h<4), Vd1
        int i = t - 32768;
        int k = i & 255, h = (i >> 8) & 3, which = i >> 10;
        const float* av = which ? a_d1 : a_s1;
        float s = 0.f;
        for (int c = 0; c < 32; ++c)
            s = fmaf(W1[(size_t)k * C1 + h * 32 + c], av[h * 32 + c], s);
        Wt1e[(size_t)(128 + which * 4 + h) * 256 + k] = (_Float16)(s * INVLN2);
    } else if (t < 36864) {                // zero pad cols 136..143
        int i = t - 34816;
        int k = i & 255, c = 136 + (i >> 8);
        Wt1e[(size_t)c * 256 + k] = (_Float16)0.f;
    } else if (t < 45056) {                // Wt2e cols 0..63 (transpose W2)
        int i = t - 36864;
        int c = i >> 7, k = i & 127;
        Wt2e[(size_t)c * 128 + k] = (_Float16)W2[(size_t)k * OUT_CH + c];
    } else if (t < 45312) {                // cols 64,65: Va2, Vd2
        int i = t - 45056;
        int k = i & 127, which = i >> 7;
        const float* av = which ? a_d2 : a_s2;
        float s = 0.f;
        for (int c = 0; c < 64; ++c)
            s = fmaf(W2[(size_t)k * OUT_CH + c], av[c], s);
        Wt2e[(size_t)(64 + which) * 128 + k] = (_Float16)(s * INVLN2);
    } else if (t < 47104) {                // zero pad cols 66..79
        int i = t - 45312;
        int k = i & 127, c = 66 + (i >> 7);
        Wt2e[(size_t)c * 128 + k] = (_Float16)0.f;
    }
}

// ====== MFMA GEMM layer1: [h1 | as | ad] = X @ Wt1e ======
// 128-row tile, 512 threads (8 waves), 9 tiles/wave. Halves B-staging vs 64-row.
__global__ __launch_bounds__(512) void gemm1_mfma(const float* __restrict__ X,
                                                  const _Float16* __restrict__ Wt1e,
                                                  __half* __restrict__ H,
                                                  float* __restrict__ as_n,
                                                  float* __restrict__ ad_n) {
    __shared__ _Float16 As[128 * 40];
    __shared__ _Float16 Bt[N1E * 40];
    const int tid = threadIdx.x;
    const int w = tid >> 6, lane = tid & 63;
    const int row0 = blockIdx.x * 128;
    const int lr = lane & 15, lk = (lane >> 4) * 8;
    f32x4 acc[9];
#pragma unroll
    for (int n = 0; n < 9; ++n) acc[n] = (f32x4){0.f, 0.f, 0.f, 0.f};

    for (int kk = 0; kk < IN_CH; kk += 32) {
        {   // stage A: 128x32 f32 -> fp16 (512 threads, 1 h8 each)
            int ar = tid >> 2, aks = (tid & 3) * 8;
            int gr = row0 + ar;
            float4 v0 = make_float4(0.f, 0.f, 0.f, 0.f), v1 = v0;
            if (gr < N_NODES) {
                v0 = *(const float4*)(X + (size_t)gr * IN_CH + kk + aks);
                v1 = *(const float4*)(X + (size_t)gr * IN_CH + kk + aks + 4);
            }
            h8 hv;
            hv[0] = (_Float16)v0.x; hv[1] = (_Float16)v0.y;
            hv[2] = (_Float16)v0.z; hv[3] = (_Float16)v0.w;
            hv[4] = (_Float16)v1.x; hv[5] = (_Float16)v1.y;
            hv[6] = (_Float16)v1.z; hv[7] = (_Float16)v1.w;
            *(h8*)(&As[ar * 40 + aks]) = hv;
        }
        // stage B chunk: 2 threads per col (288 active), 2 h8 each
        if (tid < 2 * N1E) {
            int c = tid >> 1, q = tid & 1;
            const h8* wp = (const h8*)(Wt1e + (size_t)c * IN_CH + kk + q * 16);
            *(h8*)(&Bt[c * 40 + q * 16]) = wp[0];
            *(h8*)(&Bt[c * 40 + q * 16 + 8]) = wp[1];
        }
        __syncthreads();
        h8 a = *(const h8*)(&As[(w * 16 + lr) * 40 + lk]);
#pragma unroll
        for (int n = 0; n < 9; ++n) {
            h8 b = *(const h8*)(&Bt[(n * 16 + lr) * 40 + lk]);
            acc[n] = __builtin_amdgcn_mfma_f32_16x16x32_f16(a, b, acc[n], 0, 0, 0);
        }
        __syncthreads();
    }
    // C write (fp16), tiles 0..7
#pragma unroll
    for (int n = 0; n < 8; ++n)
#pragma unroll
        for (int j = 0; j < 4; ++j) {
            int gr = row0 + w * 16 + (lane >> 4) * 4 + j;
            if (gr < N_NODES) H[(size_t)gr * C1 + n * 16 + lr] = __float2half(acc[n][j]);
        }
    // tile 8 = coefs: lr<4: as[head=lr], lr in [4,8): ad[head=lr-4]
#pragma unroll
    for (int j = 0; j < 4; ++j) {
        int gr = row0 + w * 16 + (lane >> 4) * 4 + j;
        if (gr < N_NODES) {
            if (lr < 4) as_n[gr * 4 + lr] = acc[8][j];
            else if (lr < 8) ad_n[gr * 4 + (lr - 4)] = acc[8][j];
        }
    }
}

// ====== MFMA GEMM layer2: [h2 | as2 | ad2] = hrelu @ Wt2e ======
// 128-row tile, 512 threads; B (80x128) staged once per block.
__global__ __launch_bounds__(512) void gemm2_mfma(const __half* __restrict__ A,
                                                  const _Float16* __restrict__ Wt2e,
                                                  __half* __restrict__ H,
                                                  float* __restrict__ as_n,
                                                  float* __restrict__ ad_n) {
    __shared__ _Float16 Bt[N2E * 136];
    const int tid = threadIdx.x;
    const int w = tid >> 6, lane = tid & 63;
    const int row0 = blockIdx.x * 128;
    const int lr = lane & 15, lk = (lane >> 4) * 8;
    if (tid < 160) {
        int c = tid >> 1, q = tid & 1;
        const h8* wp = (const h8*)(Wt2e + (size_t)c * C1 + q * 64);
#pragma unroll
        for (int j = 0; j < 8; ++j)
            *(h8*)(&Bt[c * 136 + q * 64 + j * 8]) = wp[j];
    }
    __syncthreads();
    f32x4 acc[5];
#pragma unroll
    for (int n = 0; n < 5; ++n) acc[n] = (f32x4){0.f, 0.f, 0.f, 0.f};
    int grow = row0 + w * 16 + lr;
    grow = grow < N_NODES ? grow : N_NODES - 1;
    const _Float16* Ah = (const _Float16*)A;
#pragma unroll
    for (int kk = 0; kk < C1; kk += 32) {
        h8 a = *(const h8*)(Ah + (size_t)grow * C1 + kk + lk);
#pragma unroll
        for (int n = 0; n < 5; ++n) {
            h8 b = *(const h8*)(&Bt[(n * 16 + lr) * 136 + kk + lk]);
            acc[n] = __builtin_amdgcn_mfma_f32_16x16x32_f16(a, b, acc[n], 0, 0, 0);
        }
    }
#pragma unroll
    for (int n = 0; n < 4; ++n)
#pragma unroll
        for (int j = 0; j < 4; ++j) {
            int gr = row0 + w * 16 + (lane >> 4) * 4 + j;
            if (gr < N_NODES) H[(size_t)gr * OUT_CH + n * 16 + lr] = __float2half(acc[n][j]);
        }
    // tile 4 = coefs: lr==0: as2, lr==1: ad2
#pragma unroll
    for (int j = 0; j < 4; ++j) {
        int gr = row0 + w * 16 + (lane >> 4) * 4 + j;
        if (gr < N_NODES) {
            if (lr == 0) as_n[gr] = acc[4][j];
            else if (lr == 1) ad_n[gr] = acc[4][j];
        }
    }
}

// ================= CSR build (bucketed, packed-int pairs) =================
__global__ __launch_bounds__(256) void k_bucket(const int* __restrict__ src,
                                                const int* __restrict__ dst,
                                                int* __restrict__ bcur,
                                                int* __restrict__ pairs) {
    __shared__ int cnt[NBKT];
    __shared__ int base[NBKT];
    const int t = threadIdx.x;
    if (t < NBKT) cnt[t] = 0;
    __syncthreads();
    const int e0 = blockIdx.x * 2048;
    int s[8], d[8], r[8];
#pragma unroll
    for (int k = 0; k < 8; ++k) {
        int e = e0 + t + k * 256;
        bool v = e < N_EDGES;
        s[k] = v ? src[e] : 0;
        d[k] = v ? dst[e] : -1;
        r[k] = v ? atomicAdd(&cnt[d[k] >> BSHIFT], 1) : 0;
    }
    __syncthreads();
    if (t < NBKT) base[t] = atomicAdd(&bcur[t], cnt[t]);
    __syncthreads();
#pragma unroll
    for (int k = 0; k < 8; ++k) {
        if (d[k] >= 0) {
            int bin = d[k] >> BSHIFT;
            int pos = base[bin] + r[k];
            if (pos < (bin + 1) * BCAP)      // overflow guard (10-sigma margin)
                pairs[pos] = ((d[k] & 1023) << 16) | s[k];   // src<50000<2^16
        }
    }
}

// phase B: per-bucket histogram -> LDS scan -> LDS-cursor scatter; emits estart/eend.
__global__ __launch_bounds__(256) void k_csr(const int* __restrict__ pairs,
                                             const int* __restrict__ bcur,
                                             int* __restrict__ estart,
                                             int* __restrict__ eend,
                                             int* __restrict__ esrc) {
    __shared__ int hist[1024];
    __shared__ int cur[1024];
    __shared__ int s[256];
    const int b = blockIdx.x;
    const int t = threadIdx.x;
#pragma unroll
    for (int k = t; k < 1024; k += 256) hist[k] = 0;
    __syncthreads();
    int cnt = bcur[b] - b * BCAP;
    if (cnt > BCAP) cnt = BCAP;
    const int* p = pairs + (size_t)b * BCAP;
    for (int i = t; i < cnt; i += 256)
        atomicAdd(&hist[p[i] >> 16], 1);
    __syncthreads();
    int h0 = hist[4 * t], h1 = hist[4 * t + 1], h2 = hist[4 * t + 2], h3 = hist[4 * t + 3];
    int sum = h0 + h1 + h2 + h3;
    s[t] = sum;
    __syncthreads();
#pragma unroll
    for (int o = 1; o < 256; o <<= 1) {
        int v = (t >= o) ? s[t - o] : 0;
        __syncthreads();
        s[t] += v;
        __syncthreads();
    }
    int excl = s[t] - sum;
    int gbase = b * BCAP + excl;
    cur[4 * t]     = gbase;
    cur[4 * t + 1] = gbase + h0;
    cur[4 * t + 2] = gbase + h0 + h1;
    cur[4 * t + 3] = gbase + h0 + h1 + h2;
    const int nbase = b << BSHIFT;
#pragma unroll
    for (int i = 0; i < 4; ++i) {
        int node = nbase + 4 * t + i;
        if (node < N_NODES) {
            int st = cur[4 * t + i];
            estart[node] = st;
            eend[node] = st + hist[4 * t + i];
        }
    }
    __syncthreads();
    for (int i = t; i < cnt; i += 256) {
        int v = p[i];
        int pos = atomicAdd(&cur[v >> 16], 1);
        esrc[pos] = v & 0xFFFF;
    }
}

// ====== aggr1 (measured-optimum config): wave per node, 16-lane quarter, 2 slots ======
__global__ __launch_bounds__(256) void gat_aggr1_csr(const int* __restrict__ estart,
                                                     const int* __restrict__ eend,
                                                     const int* __restrict__ esrc,
                                                     const float* __restrict__ as1,
                                                     const float* __restrict__ ad1,
                                                     const __half* __restrict__ h1,
                                                     const float* __restrict__ b1,
                                                     __half* __restrict__ hrelu) {
    int n = blockIdx.x * 4 + (threadIdx.x >> 6);
    if (n >= N_NODES) return;
    const int lane = threadIdx.x & 63;
    const int q = lane >> 4, li = lane & 15;
    const int head = li >> 2;
    const int c0 = li * 8;
    const int base = estart[n];
    const int end = eend[n];
    const float ad = ad1[n * 4 + head];
    const _Float16* __restrict__ H = (const _Float16*)h1;
    float den0 = 0.f, den1 = 0.f;
    float acc0[8], acc1[8];
#pragma unroll
    for (int k = 0; k < 8; ++k) { acc0[k] = 0.f; acc1[k] = 0.f; }

    for (int b0 = base; b0 < end; b0 += 64) {
        int cnt = end - b0; if (cnt > 64) cnt = 64;
        int myidx = (lane < cnt) ? esrc[b0 + lane] : 0;
        for (int it = 0; it < cnt; it += 8) {
            int j0 = it + q * 2, j1 = j0 + 1;
            bool p0 = j0 < cnt, p1 = j1 < cnt;
            int s0 = __shfl(myidx, p0 ? j0 : 0);
            int s1 = __shfl(myidx, p1 ? j1 : 0);
            float x0 = as1[s0 * 4 + head] + ad;
            x0 = x0 > 0.f ? x0 : NEG * x0;
            float w0 = p0 ? exp2f(x0) : 0.f;     // coefs pre-scaled by 1/ln2
            float x1 = as1[s1 * 4 + head] + ad;
            x1 = x1 > 0.f ? x1 : NEG * x1;
            float w1 = p1 ? exp2f(x1) : 0.f;
            h8 hv0 = *(const h8*)(H + (size_t)s0 * C1 + c0);
            h8 hv1 = *(const h8*)(H + (size_t)s1 * C1 + c0);
            den0 += w0;
            den1 += w1;
#pragma unroll
            for (int k = 0; k < 8; ++k) {
                acc0[k] = fmaf((float)hv0[k], w0, acc0[k]);
                acc1[k] = fmaf((float)hv1[k], w1, acc1[k]);
            }
        }
    }
    float den = den0 + den1;
    float r[8];
#pragma unroll
    for (int k = 0; k < 8; ++k) r[k] = acc0[k] + acc1[k];
    den += __shfl_xor(den, 16);
    den += __shfl_xor(den, 32);
#pragma unroll
    for (int k = 0; k < 8; ++k) {
        r[k] += __shfl_xor(r[k], 16);
        r[k] += __shfl_xor(r[k], 32);
    }
    if (q == 0) {
        float4 bb0 = *(const float4*)(b1 + c0);
        float4 bb1 = *(const float4*)(b1 + c0 + 4);
        float bv[8] = {bb0.x, bb0.y, bb0.z, bb0.w, bb1.x, bb1.y, bb1.z, bb1.w};
        float inv = 1.f / (den + 1e-16f);
        h8 o;
#pragma unroll
        for (int k = 0; k < 8; ++k) {
            float v = fmaf(r[k], inv, bv[k]);
            o[k] = (_Float16)(v > 0.f ? v : 0.f);
        }
        *(h8*)((_Float16*)hrelu + (size_t)n * C1 + c0) = o;
    }
}

// ====== aggr2: wave per node, 8-lane group per edge, 2 slots ======
__global__ __launch_bounds__(256) void gat_aggr2_csr(const int* __restrict__ estart,
                                                     const int* __restrict__ eend,
                                                     const int* __restrict__ esrc,
                                                     const float* __restrict__ as2,
                                                     const float* __restrict__ ad2,
                                                     const __half* __restrict__ h2,
                                                     const float* __restrict__ b2,
                                                     float* __restrict__ out) {
    int n = blockIdx.x * 4 + (threadIdx.x >> 6);
    if (n >= N_NODES) return;
    const int lane = threadIdx.x & 63;
    const int q = lane >> 3, li = lane & 7;
    const int c0 = li * 8;
    const int base = estart[n];
    const int end = eend[n];
    const float ad = ad2[n];
    const _Float16* __restrict__ H = (const _Float16*)h2;
    float den0 = 0.f, den1 = 0.f;
    float acc0[8], acc1[8];
#pragma unroll
    for (int k = 0; k < 8; ++k) { acc0[k] = 0.f; acc1[k] = 0.f; }

    for (int b0 = base; b0 < end; b0 += 64) {
        int cnt = end - b0; if (cnt > 64) cnt = 64;
        int myidx = (lane < cnt) ? esrc[b0 + lane] : 0;
        for (int it = 0; it < cnt; it += 16) {
            int j0 = it + q * 2, j1 = j0 + 1;
            bool p0 = j0 < cnt, p1 = j1 < cnt;
            int s0 = __shfl(myidx, p0 ? j0 : 0);
            int s1 = __shfl(myidx, p1 ? j1 : 0);
            float x0 = as2[s0] + ad;
            x0 = x0 > 0.f ? x0 : NEG * x0;
            float w0 = p0 ? exp2f(x0) : 0.f;
            float x1 = as2[s1] + ad;
            x1 = x1 > 0.f ? x1 : NEG * x1;
            float w1 = p1 ? exp2f(x1) : 0.f;
            h8 hv0 = *(const h8*)(H + (size_t)s0 * OUT_CH + c0);
            h8 hv1 = *(const h8*)(H + (size_t)s1 * OUT_CH + c0);
            den0 += w0;
            den1 += w1;
#pragma unroll
            for (int k = 0; k < 8; ++k) {
                acc0[k] = fmaf((float)hv0[k], w0, acc0[k]);
                acc1[k] = fmaf((float)hv1[k], w1, acc1[k]);
            }
        }
    }
    float den = den0 + den1;
    float r[8];
#pragma unroll
    for (int k = 0; k < 8; ++k) r[k] = acc0[k] + acc1[k];
    den += __shfl_xor(den, 8);
    den += __shfl_xor(den, 16);
    den += __shfl_xor(den, 32);
#pragma unroll
    for (int k = 0; k < 8; ++k) {
        r[k] += __shfl_xor(r[k], 8);
        r[k] += __shfl_xor(r[k], 16);
        r[k] += __shfl_xor(r[k], 32);
    }
    if (q == 0) {
        float4 bb0 = *(const float4*)(b2 + c0);
        float4 bb1 = *(const float4*)(b2 + c0 + 4);
        float inv = 1.f / (den + 1e-16f);
        float4 o0, o1;
        o0.x = fmaf(r[0], inv, bb0.x);
        o0.y = fmaf(r[1], inv, bb0.y);
        o0.z = fmaf(r[2], inv, bb0.z);
        o0.w = fmaf(r[3], inv, bb0.w);
        o1.x = fmaf(r[4], inv, bb1.x);
        o1.y = fmaf(r[5], inv, bb1.y);
        o1.z = fmaf(r[6], inv, bb1.z);
        o1.w = fmaf(r[7], inv, bb1.w);
        *(float4*)(out + (size_t)n * OUT_CH + c0) = o0;
        *(float4*)(out + (size_t)n * OUT_CH + c0 + 4) = o1;
    }
}

extern "C" void kernel_launch(void* const* d_in, const int* in_sizes, int n_in,
                              void* d_out, int out_size, void* d_ws, size_t ws_size,
                              hipStream_t stream) {
    const float* x      = (const float*)d_in[0];
    const int*   ei     = (const int*)d_in[1];
    const float* W1     = (const float*)d_in[2];
    const float* a_src1 = (const float*)d_in[3];
    const float* a_dst1 = (const float*)d_in[4];
    const float* b1     = (const float*)d_in[5];
    const float* W2     = (const float*)d_in[6];
    const float* a_src2 = (const float*)d_in[7];
    const float* a_dst2 = (const float*)d_in[8];
    const float* b2     = (const float*)d_in[9];
    float* out = (float*)d_out;

    const int* src = ei;
    const int* dst = ei + N_EDGES;

    char* w = (char*)d_ws;
    auto carve = [&](size_t bytes) {
        char* p = w;
        w += (bytes + 255) & ~(size_t)255;
        return p;
    };
    __half*   h1     = (__half*)carve((size_t)N_NODES * C1 * 2);   // phase2: h2 aliases
    __half*   hrelu  = (__half*)carve((size_t)N_NODES * C1 * 2);
    float*    as1    = (float*)carve((size_t)N_NODES * 4 * 4);     // phase2: as2
    float*    ad1    = (float*)carve((size_t)N_NODES * 4 * 4);     // phase2: ad2
    int*      estart = (int*)carve((size_t)N_NODES * 4);
    int*      eend   = (int*)carve((size_t)N_NODES * 4);
    int*      esrc   = (int*)carve((size_t)NBKT * BCAP * 4);
    int*      bcur   = (int*)carve((size_t)NBKT * 4);
    int*      pairs  = (int*)carve((size_t)NBKT * BCAP * 4);
    _Float16* Wt1e   = (_Float16*)carve((size_t)N1E * IN_CH * 2);
    _Float16* Wt2e   = (_Float16*)carve((size_t)N2E * C1 * 2);

    __half* h2  = h1;
    float*  as2 = as1;
    float*  ad2 = ad1;

    // ---- CSR build + weight prep (3 kernels; shared by both layers) ----
    k_prep<<<184, 256, 0, stream>>>(W1, W2, a_src1, a_dst1, a_src2, a_dst2,
                                    Wt1e, Wt2e, bcur);
    k_bucket<<<(N_EDGES + 2047) / 2048, 256, 0, stream>>>(src, dst, bcur, pairs);
    k_csr<<<NBKT, 256, 0, stream>>>(pairs, bcur, estart, eend, esrc);

    // ---- layer 1 ----
    gemm1_mfma<<<(N_NODES + 127) / 128, 512, 0, stream>>>(x, Wt1e, h1, as1, ad1);
    gat_aggr1_csr<<<(N_NODES + 3) / 4, 256, 0, stream>>>(estart, eend, esrc, as1, ad1, h1, b1, hrelu);

    // ---- layer 2 ----
    gemm2_mfma<<<(N_NODES + 127) / 128, 512, 0, stream>>>(hrelu, Wt2e, h2, as2, ad2);
    gat_aggr2_csr<<<(N_NODES + 3) / 4, 256, 0, stream>>>(estart, eend, esrc, as2, ad2, h2, b2, out);

    (void)in_sizes; (void)n_in; (void)out_size; (void)ws_size;
}

// Round 16
// 134.098 us; speedup vs baseline: 1.2631x; 1.1587x over previous
//
#include <hip/hip_runtime.h>
#include <hip/hip_fp16.h>

#define N_NODES 50000
#define N_EDGES 800000
#define IN_CH   256
#define HID     32
#define HEADS1  4
#define C1      128      // HEADS1*HID
#define OUT_CH  64
#define NEG     0.2f
#define INVLN2  1.4426950408889634f
#define BSHIFT  10
#define NBKT    49                        // ceil(50000/1024)
#define BCAP    17664                     // mean 16327 + ~10 sigma
#define N1E     144                       // 128 h-cols + 4 as + 4 ad + 8 pad
#define N2E     80                        // 64 h-cols + as + ad + 14 pad

typedef _Float16 h8 __attribute__((ext_vector_type(8)));
typedef float f32x4 __attribute__((ext_vector_type(4)));

// ===== weight prep: fp16 transposed W + attention-vector columns + bcur init =====
__global__ void k_prep(const float* __restrict__ W1, const float* __restrict__ W2,
                       const float* __restrict__ a_s1, const float* __restrict__ a_d1,
                       const float* __restrict__ a_s2, const float* __restrict__ a_d2,
                       _Float16* __restrict__ Wt1e, _Float16* __restrict__ Wt2e,
                       int* __restrict__ bcur) {
    int t = blockIdx.x * 256 + threadIdx.x;
    if (blockIdx.x == 0 && threadIdx.x < NBKT) bcur[threadIdx.x] = threadIdx.x * BCAP;
    if (t < 32768) {                       // Wt1e cols 0..127 (transpose W1)
        int c = t >> 8, k = t & 255;
        Wt1e[(size_t)c * 256 + k] = (_Float16)W1[(size_t)k * C1 + c];
    } else if (t < 34816) {                // cols 128..135: Va1 (h<4), Vd1
        int i = t - 32768;
        int k = i & 255, h = (i >> 8) & 3, which = i >> 10;
        const float* av = which ? a_d1 : a_s1;
        float s = 0.f;
        for (int c = 0; c < 32; ++c)
            s = fmaf(W1[(size_t)k * C1 + h * 32 + c], av[h * 32 + c], s);
        Wt1e[(size_t)(128 + which * 4 + h) * 256 + k] = (_Float16)(s * INVLN2);
    } else if (t < 36864) {                // zero pad cols 136..143
        int i = t - 34816;
        int k = i & 255, c = 136 + (i >> 8);
        Wt1e[(size_t)c * 256 + k] = (_Float16)0.f;
    } else if (t < 45056) {                // Wt2e cols 0..63 (transpose W2)
        int i = t - 36864;
        int c = i >> 7, k = i & 127;
        Wt2e[(size_t)c * 128 + k] = (_Float16)W2[(size_t)k * OUT_CH + c];
    } else if (t < 45312) {                // cols 64,65: Va2, Vd2
        int i = t - 45056;
        int k = i & 127, which = i >> 7;
        const float* av = which ? a_d2 : a_s2;
        float s = 0.f;
        for (int c = 0; c < 64; ++c)
            s = fmaf(W2[(size_t)k * OUT_CH + c], av[c], s);
        Wt2e[(size_t)(64 + which) * 128 + k] = (_Float16)(s * INVLN2);
    } else if (t < 47104) {                // zero pad cols 66..79
        int i = t - 45312;
        int k = i & 127, c = 66 + (i >> 7);
        Wt2e[(size_t)c * 128 + k] = (_Float16)0.f;
    }
}

// ====== MFMA GEMM layer1: [h1 | as | ad] = X @ Wt1e (128-row tile, 512 thr) ======
__global__ __launch_bounds__(512) void gemm1_mfma(const float* __restrict__ X,
                                                  const _Float16* __restrict__ Wt1e,
                                                  __half* __restrict__ H,
                                                  float* __restrict__ as_n,
                                                  float* __restrict__ ad_n) {
    __shared__ _Float16 As[128 * 40];
    __shared__ _Float16 Bt[N1E * 40];
    const int tid = threadIdx.x;
    const int w = tid >> 6, lane = tid & 63;
    const int row0 = blockIdx.x * 128;
    const int lr = lane & 15, lk = (lane >> 4) * 8;
    f32x4 acc[9];
#pragma unroll
    for (int n = 0; n < 9; ++n) acc[n] = (f32x4){0.f, 0.f, 0.f, 0.f};

    for (int kk = 0; kk < IN_CH; kk += 32) {
        {   // stage A: 128x32 f32 -> fp16 (512 threads, 1 h8 each)
            int ar = tid >> 2, aks = (tid & 3) * 8;
            int gr = row0 + ar;
            float4 v0 = make_float4(0.f, 0.f, 0.f, 0.f), v1 = v0;
            if (gr < N_NODES) {
                v0 = *(const float4*)(X + (size_t)gr * IN_CH + kk + aks);
                v1 = *(const float4*)(X + (size_t)gr * IN_CH + kk + aks + 4);
            }
            h8 hv;
            hv[0] = (_Float16)v0.x; hv[1] = (_Float16)v0.y;
            hv[2] = (_Float16)v0.z; hv[3] = (_Float16)v0.w;
            hv[4] = (_Float16)v1.x; hv[5] = (_Float16)v1.y;
            hv[6] = (_Float16)v1.z; hv[7] = (_Float16)v1.w;
            *(h8*)(&As[ar * 40 + aks]) = hv;
        }
        if (tid < 2 * N1E) {
            int c = tid >> 1, q = tid & 1;
            const h8* wp = (const h8*)(Wt1e + (size_t)c * IN_CH + kk + q * 16);
            *(h8*)(&Bt[c * 40 + q * 16]) = wp[0];
            *(h8*)(&Bt[c * 40 + q * 16 + 8]) = wp[1];
        }
        __syncthreads();
        h8 a = *(const h8*)(&As[(w * 16 + lr) * 40 + lk]);
#pragma unroll
        for (int n = 0; n < 9; ++n) {
            h8 b = *(const h8*)(&Bt[(n * 16 + lr) * 40 + lk]);
            acc[n] = __builtin_amdgcn_mfma_f32_16x16x32_f16(a, b, acc[n], 0, 0, 0);
        }
        __syncthreads();
    }
#pragma unroll
    for (int n = 0; n < 8; ++n)
#pragma unroll
        for (int j = 0; j < 4; ++j) {
            int gr = row0 + w * 16 + (lane >> 4) * 4 + j;
            if (gr < N_NODES) H[(size_t)gr * C1 + n * 16 + lr] = __float2half(acc[n][j]);
        }
#pragma unroll
    for (int j = 0; j < 4; ++j) {
        int gr = row0 + w * 16 + (lane >> 4) * 4 + j;
        if (gr < N_NODES) {
            if (lr < 4) as_n[gr * 4 + lr] = acc[8][j];
            else if (lr < 8) ad_n[gr * 4 + (lr - 4)] = acc[8][j];
        }
    }
}

// ====== MFMA GEMM layer2: [h2 | as2 | ad2] = hrelu @ Wt2e (128-row tile) ======
__global__ __launch_bounds__(512) void gemm2_mfma(const __half* __restrict__ A,
                                                  const _Float16* __restrict__ Wt2e,
                                                  __half* __restrict__ H,
                                                  float* __restrict__ as_n,
                                                  float* __restrict__ ad_n) {
    __shared__ _Float16 Bt[N2E * 136];
    const int tid = threadIdx.x;
    const int w = tid >> 6, lane = tid & 63;
    const int row0 = blockIdx.x * 128;
    const int lr = lane & 15, lk = (lane >> 4) * 8;
    if (tid < 160) {
        int c = tid >> 1, q = tid & 1;
        const h8* wp = (const h8*)(Wt2e + (size_t)c * C1 + q * 64);
#pragma unroll
        for (int j = 0; j < 8; ++j)
            *(h8*)(&Bt[c * 136 + q * 64 + j * 8]) = wp[j];
    }
    __syncthreads();
    f32x4 acc[5];
#pragma unroll
    for (int n = 0; n < 5; ++n) acc[n] = (f32x4){0.f, 0.f, 0.f, 0.f};
    int grow = row0 + w * 16 + lr;
    grow = grow < N_NODES ? grow : N_NODES - 1;
    const _Float16* Ah = (const _Float16*)A;
#pragma unroll
    for (int kk = 0; kk < C1; kk += 32) {
        h8 a = *(const h8*)(Ah + (size_t)grow * C1 + kk + lk);
#pragma unroll
        for (int n = 0; n < 5; ++n) {
            h8 b = *(const h8*)(&Bt[(n * 16 + lr) * 136 + kk + lk]);
            acc[n] = __builtin_amdgcn_mfma_f32_16x16x32_f16(a, b, acc[n], 0, 0, 0);
        }
    }
#pragma unroll
    for (int n = 0; n < 4; ++n)
#pragma unroll
        for (int j = 0; j < 4; ++j) {
            int gr = row0 + w * 16 + (lane >> 4) * 4 + j;
            if (gr < N_NODES) H[(size_t)gr * OUT_CH + n * 16 + lr] = __float2half(acc[n][j]);
        }
#pragma unroll
    for (int j = 0; j < 4; ++j) {
        int gr = row0 + w * 16 + (lane >> 4) * 4 + j;
        if (gr < N_NODES) {
            if (lr == 0) as_n[gr] = acc[4][j];
            else if (lr == 1) ad_n[gr] = acc[4][j];
        }
    }
}

// ================= CSR build =================
// k_bucket: per-WAVE LDS histograms (4x49 -> ~4x less same-address contention),
// int4 vector loads (8 consecutive edges/thread; N_EDGES%8==0).
__global__ __launch_bounds__(256) void k_bucket(const int* __restrict__ src,
                                                const int* __restrict__ dst,
                                                int* __restrict__ bcur,
                                                int* __restrict__ pairs) {
    __shared__ int cnt[4 * NBKT];
    __shared__ int base[4 * NBKT];
    const int t = threadIdx.x;
    const int w = t >> 6;
    for (int i = t; i < 4 * NBKT; i += 256) cnt[i] = 0;
    __syncthreads();
    const int e0 = blockIdx.x * 2048 + t * 8;
    int s[8], d[8], r[8];
    bool valid = e0 + 7 < N_EDGES;   // chunks of 8 are all-or-nothing (800000%8==0)
    if (valid) {
        int4 sa = *(const int4*)(src + e0);
        int4 sb = *(const int4*)(src + e0 + 4);
        int4 da = *(const int4*)(dst + e0);
        int4 db = *(const int4*)(dst + e0 + 4);
        s[0] = sa.x; s[1] = sa.y; s[2] = sa.z; s[3] = sa.w;
        s[4] = sb.x; s[5] = sb.y; s[6] = sb.z; s[7] = sb.w;
        d[0] = da.x; d[1] = da.y; d[2] = da.z; d[3] = db.x - 0;  // placeholder fix below
        d[3] = da.w;
        d[4] = db.x; d[5] = db.y; d[6] = db.z; d[7] = db.w;
#pragma unroll
        for (int k = 0; k < 8; ++k)
            r[k] = atomicAdd(&cnt[w * NBKT + (d[k] >> BSHIFT)], 1);
    }
    __syncthreads();
    if (t < NBKT) {
        int c0 = cnt[0 * NBKT + t], c1 = cnt[1 * NBKT + t];
        int c2 = cnt[2 * NBKT + t], c3 = cnt[3 * NBKT + t];
        int g = atomicAdd(&bcur[t], c0 + c1 + c2 + c3);
        base[0 * NBKT + t] = g;
        base[1 * NBKT + t] = g + c0;
        base[2 * NBKT + t] = g + c0 + c1;
        base[3 * NBKT + t] = g + c0 + c1 + c2;
    }
    __syncthreads();
    if (valid) {
#pragma unroll
        for (int k = 0; k < 8; ++k) {
            int bin = d[k] >> BSHIFT;
            int pos = base[w * NBKT + bin] + r[k];
            if (pos < (bin + 1) * BCAP)      // overflow guard (10-sigma margin)
                pairs[pos] = ((d[k] & 1023) << 16) | s[k];   // src<50000<2^16
        }
    }
}

// k_csr: per-bucket histogram -> LDS scan -> LDS-cursor scatter; int4 passes.
__global__ __launch_bounds__(256) void k_csr(const int* __restrict__ pairs,
                                             const int* __restrict__ bcur,
                                             int* __restrict__ estart,
                                             int* __restrict__ eend,
                                             int* __restrict__ esrc) {
    __shared__ int hist[1024];
    __shared__ int cur[1024];
    __shared__ int s[256];
    const int b = blockIdx.x;
    const int t = threadIdx.x;
#pragma unroll
    for (int k = t; k < 1024; k += 256) hist[k] = 0;
    __syncthreads();
    int cnt = bcur[b] - b * BCAP;
    if (cnt > BCAP) cnt = BCAP;
    const int* p = pairs + (size_t)b * BCAP;
    const int cnt4 = cnt & ~3;
    for (int i = t * 4; i < cnt4; i += 1024) {
        int4 v = *(const int4*)(p + i);
        atomicAdd(&hist[v.x >> 16], 1);
        atomicAdd(&hist[v.y >> 16], 1);
        atomicAdd(&hist[v.z >> 16], 1);
        atomicAdd(&hist[v.w >> 16], 1);
    }
    for (int i = cnt4 + t; i < cnt; i += 256)
        atomicAdd(&hist[p[i] >> 16], 1);
    __syncthreads();
    int h0 = hist[4 * t], h1 = hist[4 * t + 1], h2 = hist[4 * t + 2], h3 = hist[4 * t + 3];
    int sum = h0 + h1 + h2 + h3;
    s[t] = sum;
    __syncthreads();
#pragma unroll
    for (int o = 1; o < 256; o <<= 1) {
        int v = (t >= o) ? s[t - o] : 0;
        __syncthreads();
        s[t] += v;
        __syncthreads();
    }
    int excl = s[t] - sum;
    int gbase = b * BCAP + excl;
    cur[4 * t]     = gbase;
    cur[4 * t + 1] = gbase + h0;
    cur[4 * t + 2] = gbase + h0 + h1;
    cur[4 * t + 3] = gbase + h0 + h1 + h2;
    const int nbase = b << BSHIFT;
#pragma unroll
    for (int i = 0; i < 4; ++i) {
        int node = nbase + 4 * t + i;
        if (node < N_NODES) {
            int st = cur[4 * t + i];
            estart[node] = st;
            eend[node] = st + hist[4 * t + i];
        }
    }
    __syncthreads();
    for (int i = t * 4; i < cnt4; i += 1024) {
        int4 v = *(const int4*)(p + i);
        esrc[atomicAdd(&cur[v.x >> 16], 1)] = v.x & 0xFFFF;
        esrc[atomicAdd(&cur[v.y >> 16], 1)] = v.y & 0xFFFF;
        esrc[atomicAdd(&cur[v.z >> 16], 1)] = v.z & 0xFFFF;
        esrc[atomicAdd(&cur[v.w >> 16], 1)] = v.w & 0xFFFF;
    }
    for (int i = cnt4 + t; i < cnt; i += 256) {
        int v = p[i];
        esrc[atomicAdd(&cur[v >> 16], 1)] = v & 0xFFFF;
    }
}

// ====== aggr1 (measured-optimum): wave per node, 16-lane quarter, 2 slots ======
__global__ __launch_bounds__(256) void gat_aggr1_csr(const int* __restrict__ estart,
                                                     const int* __restrict__ eend,
                                                     const int* __restrict__ esrc,
                                                     const float* __restrict__ as1,
                                                     const float* __restrict__ ad1,
                                                     const __half* __restrict__ h1,
                                                     const float* __restrict__ b1,
                                                     __half* __restrict__ hrelu) {
    int n = blockIdx.x * 4 + (threadIdx.x >> 6);
    if (n >= N_NODES) return;
    const int lane = threadIdx.x & 63;
    const int q = lane >> 4, li = lane & 15;
    const int head = li >> 2;
    const int c0 = li * 8;
    const int base = estart[n];
    const int end = eend[n];
    const float ad = ad1[n * 4 + head];
    const _Float16* __restrict__ H = (const _Float16*)h1;
    float den0 = 0.f, den1 = 0.f;
    float acc0[8], acc1[8];
#pragma unroll
    for (int k = 0; k < 8; ++k) { acc0[k] = 0.f; acc1[k] = 0.f; }

    for (int b0 = base; b0 < end; b0 += 64) {
        int cnt = end - b0; if (cnt > 64) cnt = 64;
        int myidx = (lane < cnt) ? esrc[b0 + lane] : 0;
        for (int it = 0; it < cnt; it += 8) {
            int j0 = it + q * 2, j1 = j0 + 1;
            bool p0 = j0 < cnt, p1 = j1 < cnt;
            int s0 = __shfl(myidx, p0 ? j0 : 0);
            int s1 = __shfl(myidx, p1 ? j1 : 0);
            float x0 = as1[s0 * 4 + head] + ad;
            x0 = x0 > 0.f ? x0 : NEG * x0;
            float w0 = p0 ? exp2f(x0) : 0.f;     // coefs pre-scaled by 1/ln2
            float x1 = as1[s1 * 4 + head] + ad;
            x1 = x1 > 0.f ? x1 : NEG * x1;
            float w1 = p1 ? exp2f(x1) : 0.f;
            h8 hv0 = *(const h8*)(H + (size_t)s0 * C1 + c0);
            h8 hv1 = *(const h8*)(H + (size_t)s1 * C1 + c0);
            den0 += w0;
            den1 += w1;
#pragma unroll
            for (int k = 0; k < 8; ++k) {
                acc0[k] = fmaf((float)hv0[k], w0, acc0[k]);
                acc1[k] = fmaf((float)hv1[k], w1, acc1[k]);
            }
        }
    }
    float den = den0 + den1;
    float r[8];
#pragma unroll
    for (int k = 0; k < 8; ++k) r[k] = acc0[k] + acc1[k];
    den += __shfl_xor(den, 16);
    den += __shfl_xor(den, 32);
#pragma unroll
    for (int k = 0; k < 8; ++k) {
        r[k] += __shfl_xor(r[k], 16);
        r[k] += __shfl_xor(r[k], 32);
    }
    if (q == 0) {
        float4 bb0 = *(const float4*)(b1 + c0);
        float4 bb1 = *(const float4*)(b1 + c0 + 4);
        float bv[8] = {bb0.x, bb0.y, bb0.z, bb0.w, bb1.x, bb1.y, bb1.z, bb1.w};
        float inv = 1.f / (den + 1e-16f);
        h8 o;
#pragma unroll
        for (int k = 0; k < 8; ++k) {
            float v = fmaf(r[k], inv, bv[k]);
            o[k] = (_Float16)(v > 0.f ? v : 0.f);
        }
        *(h8*)((_Float16*)hrelu + (size_t)n * C1 + c0) = o;
    }
}

// ====== aggr2: wave per node, 8-lane group per edge, 2 slots ======
__global__ __launch_bounds__(256) void gat_aggr2_csr(const int* __restrict__ estart,
                                                     const int* __restrict__ eend,
                                                     const int* __restrict__ esrc,
                                                     const float* __restrict__ as2,
                                                     const float* __restrict__ ad2,
                                                     const __half* __restrict__ h2,
                                                     const float* __restrict__ b2,
                                                     float* __restrict__ out) {
    int n = blockIdx.x * 4 + (threadIdx.x >> 6);
    if (n >= N_NODES) return;
    const int lane = threadIdx.x & 63;
    const int q = lane >> 3, li = lane & 7;
    const int c0 = li * 8;
    const int base = estart[n];
    const int end = eend[n];
    const float ad = ad2[n];
    const _Float16* __restrict__ H = (const _Float16*)h2;
    float den0 = 0.f, den1 = 0.f;
    float acc0[8], acc1[8];
#pragma unroll
    for (int k = 0; k < 8; ++k) { acc0[k] = 0.f; acc1[k] = 0.f; }

    for (int b0 = base; b0 < end; b0 += 64) {
        int cnt = end - b0; if (cnt > 64) cnt = 64;
        int myidx = (lane < cnt) ? esrc[b0 + lane] : 0;
        for (int it = 0; it < cnt; it += 16) {
            int j0 = it + q * 2, j1 = j0 + 1;
            bool p0 = j0 < cnt, p1 = j1 < cnt;
            int s0 = __shfl(myidx, p0 ? j0 : 0);
            int s1 = __shfl(myidx, p1 ? j1 : 0);
            float x0 = as2[s0] + ad;
            x0 = x0 > 0.f ? x0 : NEG * x0;
            float w0 = p0 ? exp2f(x0) : 0.f;
            float x1 = as2[s1] + ad;
            x1 = x1 > 0.f ? x1 : NEG * x1;
            float w1 = p1 ? exp2f(x1) : 0.f;
            h8 hv0 = *(const h8*)(H + (size_t)s0 * OUT_CH + c0);
            h8 hv1 = *(const h8*)(H + (size_t)s1 * OUT_CH + c0);
            den0 += w0;
            den1 += w1;
#pragma unroll
            for (int k = 0; k < 8; ++k) {
                acc0[k] = fmaf((float)hv0[k], w0, acc0[k]);
                acc1[k] = fmaf((float)hv1[k], w1, acc1[k]);
            }
        }
    }
    float den = den0 + den1;
    float r[8];
#pragma unroll
    for (int k = 0; k < 8; ++k) r[k] = acc0[k] + acc1[k];
    den += __shfl_xor(den, 8);
    den += __shfl_xor(den, 16);
    den += __shfl_xor(den, 32);
#pragma unroll
    for (int k = 0; k < 8; ++k) {
        r[k] += __shfl_xor(r[k], 8);
        r[k] += __shfl_xor(r[k], 16);
        r[k] += __shfl_xor(r[k], 32);
    }
    if (q == 0) {
        float4 bb0 = *(const float4*)(b2 + c0);
        float4 bb1 = *(const float4*)(b2 + c0 + 4);
        float inv = 1.f / (den + 1e-16f);
        float4 o0, o1;
        o0.x = fmaf(r[0], inv, bb0.x);
        o0.y = fmaf(r[1], inv, bb0.y);
        o0.z = fmaf(r[2], inv, bb0.z);
        o0.w = fmaf(r[3], inv, bb0.w);
        o1.x = fmaf(r[4], inv, bb1.x);
        o1.y = fmaf(r[5], inv, bb1.y);
        o1.z = fmaf(r[6], inv, bb1.z);
        o1.w = fmaf(r[7], inv, bb1.w);
        *(float4*)(out + (size_t)n * OUT_CH + c0) = o0;
        *(float4*)(out + (size_t)n * OUT_CH + c0 + 4) = o1;
    }
}

extern "C" void kernel_launch(void* const* d_in, const int* in_sizes, int n_in,
                              void* d_out, int out_size, void* d_ws, size_t ws_size,
                              hipStream_t stream) {
    const float* x      = (const float*)d_in[0];
    const int*   ei     = (const int*)d_in[1];
    const float* W1     = (const float*)d_in[2];
    const float* a_src1 = (const float*)d_in[3];
    const float* a_dst1 = (const float*)d_in[4];
    const float* b1     = (const float*)d_in[5];
    const float* W2     = (const float*)d_in[6];
    const float* a_src2 = (const float*)d_in[7];
    const float* a_dst2 = (const float*)d_in[8];
    const float* b2     = (const float*)d_in[9];
    float* out = (float*)d_out;

    const int* src = ei;
    const int* dst = ei + N_EDGES;

    char* w = (char*)d_ws;
    auto carve = [&](size_t bytes) {
        char* p = w;
        w += (bytes + 255) & ~(size_t)255;
        return p;
    };
    __half*   h1     = (__half*)carve((size_t)N_NODES * C1 * 2);   // phase2: h2 aliases
    __half*   hrelu  = (__half*)carve((size_t)N_NODES * C1 * 2);
    float*    as1    = (float*)carve((size_t)N_NODES * 4 * 4);     // phase2: as2
    float*    ad1    = (float*)carve((size_t)N_NODES * 4 * 4);     // phase2: ad2
    int*      estart = (int*)carve((size_t)N_NODES * 4);
    int*      eend   = (int*)carve((size_t)N_NODES * 4);
    int*      esrc   = (int*)carve((size_t)NBKT * BCAP * 4);
    int*      bcur   = (int*)carve((size_t)NBKT * 4);
    int*      pairs  = (int*)carve((size_t)NBKT * BCAP * 4);
    _Float16* Wt1e   = (_Float16*)carve((size_t)N1E * IN_CH * 2);
    _Float16* Wt2e   = (_Float16*)carve((size_t)N2E * C1 * 2);

    __half* h2  = h1;
    float*  as2 = as1;
    float*  ad2 = ad1;

    // ---- CSR build + weight prep (3 kernels; shared by both layers) ----
    k_prep<<<184, 256, 0, stream>>>(W1, W2, a_src1, a_dst1, a_src2, a_dst2,
                                    Wt1e, Wt2e, bcur);
    k_bucket<<<(N_EDGES + 2047) / 2048, 256, 0, stream>>>(src, dst, bcur, pairs);
    k_csr<<<NBKT, 256, 0, stream>>>(pairs, bcur, estart, eend, esrc);

    // ---- layer 1 ----
    gemm1_mfma<<<(N_NODES + 127) / 128, 512, 0, stream>>>(x, Wt1e, h1, as1, ad1);
    gat_aggr1_csr<<<(N_NODES + 3) / 4, 256, 0, stream>>>(estart, eend, esrc, as1, ad1, h1, b1, hrelu);

    // ---- layer 2 ----
    gemm2_mfma<<<(N_NODES + 127) / 128, 512, 0, stream>>>(hrelu, Wt2e, h2, as2, ad2);
    gat_aggr2_csr<<<(N_NODES + 3) / 4, 256, 0, stream>>>(estart, eend, esrc, as2, ad2, h2, b2, out);

    (void)in_sizes; (void)n_in; (void)out_size; (void)ws_size;
}

// Round 17
// 130.301 us; speedup vs baseline: 1.2999x; 1.0291x over previous
//
#include <hip/hip_runtime.h>
#include <hip/hip_fp16.h>

#define N_NODES 50000
#define N_EDGES 800000
#define IN_CH   256
#define HID     32
#define HEADS1  4
#define C1      128      // HEADS1*HID
#define OUT_CH  64
#define NEG     0.2f
#define INVLN2  1.4426950408889634f
#define BSHIFT  10
#define NBKT    49                        // ceil(50000/1024)
#define BCAP    17664                     // mean 16327 + ~10 sigma
#define N1E     144                       // 128 h-cols + 4 as + 4 ad + 8 pad
#define N2E     80                        // 64 h-cols + as + ad + 14 pad

typedef _Float16 h8 __attribute__((ext_vector_type(8)));
typedef float f32x4 __attribute__((ext_vector_type(4)));

// ===== weight prep: fp16 transposed W + attention-vector columns + bcur init =====
__global__ void k_prep(const float* __restrict__ W1, const float* __restrict__ W2,
                       const float* __restrict__ a_s1, const float* __restrict__ a_d1,
                       const float* __restrict__ a_s2, const float* __restrict__ a_d2,
                       _Float16* __restrict__ Wt1e, _Float16* __restrict__ Wt2e,
                       int* __restrict__ bcur) {
    int t = blockIdx.x * 256 + threadIdx.x;
    if (blockIdx.x == 0 && threadIdx.x < NBKT) bcur[threadIdx.x] = threadIdx.x * BCAP;
    if (t < 32768) {                       // Wt1e cols 0..127 (transpose W1)
        int c = t >> 8, k = t & 255;
        Wt1e[(size_t)c * 256 + k] = (_Float16)W1[(size_t)k * C1 + c];
    } else if (t < 34816) {                // cols 128..135: Va1 (h<4), Vd1
        int i = t - 32768;
        int k = i & 255, h = (i >> 8) & 3, which = i >> 10;
        const float* av = which ? a_d1 : a_s1;
        float s = 0.f;
        for (int c = 0; c < 32; ++c)
            s = fmaf(W1[(size_t)k * C1 + h * 32 + c], av[h * 32 + c], s);
        Wt1e[(size_t)(128 + which * 4 + h) * 256 + k] = (_Float16)(s * INVLN2);
    } else if (t < 36864) {                // zero pad cols 136..143
        int i = t - 34816;
        int k = i & 255, c = 136 + (i >> 8);
        Wt1e[(size_t)c * 256 + k] = (_Float16)0.f;
    } else if (t < 45056) {                // Wt2e cols 0..63 (transpose W2)
        int i = t - 36864;
        int c = i >> 7, k = i & 127;
        Wt2e[(size_t)c * 128 + k] = (_Float16)W2[(size_t)k * OUT_CH + c];
    } else if (t < 45312) {                // cols 64,65: Va2, Vd2
        int i = t - 45056;
        int k = i & 127, which = i >> 7;
        const float* av = which ? a_d2 : a_s2;
        float s = 0.f;
        for (int c = 0; c < 64; ++c)
            s = fmaf(W2[(size_t)k * OUT_CH + c], av[c], s);
        Wt2e[(size_t)(64 + which) * 128 + k] = (_Float16)(s * INVLN2);
    } else if (t < 47104) {                // zero pad cols 66..79
        int i = t - 45312;
        int k = i & 127, c = 66 + (i >> 7);
        Wt2e[(size_t)c * 128 + k] = (_Float16)0.f;
    }
}

// ====== MFMA GEMM layer1: [h1 | as | ad] = X @ Wt1e ======
// 128-row tile, 512 threads; register-prefetch software pipeline: next K-chunk's
// global loads issue right after the LDS-write barrier and overlap the MFMAs.
__global__ __launch_bounds__(512) void gemm1_mfma(const float* __restrict__ X,
                                                  const _Float16* __restrict__ Wt1e,
                                                  __half* __restrict__ H,
                                                  float* __restrict__ as_n,
                                                  float* __restrict__ ad_n) {
    __shared__ _Float16 As[128 * 40];
    __shared__ _Float16 Bt[N1E * 40];
    const int tid = threadIdx.x;
    const int w = tid >> 6, lane = tid & 63;
    const int row0 = blockIdx.x * 128;
    const int lr = lane & 15, lk = (lane >> 4) * 8;
    const int ar = tid >> 2, aks = (tid & 3) * 8;
    const int gr_a = row0 + ar;
    const bool arow_ok = gr_a < N_NODES;
    const int bc = tid >> 1, bq = tid & 1;
    const bool bcol_ok = tid < 2 * N1E;

    f32x4 acc[9];
#pragma unroll
    for (int n = 0; n < 9; ++n) acc[n] = (f32x4){0.f, 0.f, 0.f, 0.f};

    // prologue: load chunk 0
    float4 av0 = make_float4(0.f, 0.f, 0.f, 0.f), av1 = av0;
    h8 bv0 = {}, bv1 = {};
    if (arow_ok) {
        av0 = *(const float4*)(X + (size_t)gr_a * IN_CH + aks);
        av1 = *(const float4*)(X + (size_t)gr_a * IN_CH + aks + 4);
    }
    if (bcol_ok) {
        const h8* wp = (const h8*)(Wt1e + (size_t)bc * IN_CH + bq * 16);
        bv0 = wp[0];
        bv1 = wp[1];
    }

    for (int kk = 0; kk < IN_CH; kk += 32) {
        {   // write staged regs -> LDS
            h8 hv;
            hv[0] = (_Float16)av0.x; hv[1] = (_Float16)av0.y;
            hv[2] = (_Float16)av0.z; hv[3] = (_Float16)av0.w;
            hv[4] = (_Float16)av1.x; hv[5] = (_Float16)av1.y;
            hv[6] = (_Float16)av1.z; hv[7] = (_Float16)av1.w;
            *(h8*)(&As[ar * 40 + aks]) = hv;
            if (bcol_ok) {
                *(h8*)(&Bt[bc * 40 + bq * 16]) = bv0;
                *(h8*)(&Bt[bc * 40 + bq * 16 + 8]) = bv1;
            }
        }
        __syncthreads();
        // issue next chunk's global loads (overlap with MFMAs below)
        int kn = kk + 32;
        if (kn < IN_CH) {
            if (arow_ok) {
                av0 = *(const float4*)(X + (size_t)gr_a * IN_CH + kn + aks);
                av1 = *(const float4*)(X + (size_t)gr_a * IN_CH + kn + aks + 4);
            }
            if (bcol_ok) {
                const h8* wp = (const h8*)(Wt1e + (size_t)bc * IN_CH + kn + bq * 16);
                bv0 = wp[0];
                bv1 = wp[1];
            }
        }
        h8 a = *(const h8*)(&As[(w * 16 + lr) * 40 + lk]);
#pragma unroll
        for (int n = 0; n < 9; ++n) {
            h8 b = *(const h8*)(&Bt[(n * 16 + lr) * 40 + lk]);
            acc[n] = __builtin_amdgcn_mfma_f32_16x16x32_f16(a, b, acc[n], 0, 0, 0);
        }
        __syncthreads();
    }
#pragma unroll
    for (int n = 0; n < 8; ++n)
#pragma unroll
        for (int j = 0; j < 4; ++j) {
            int gr = row0 + w * 16 + (lane >> 4) * 4 + j;
            if (gr < N_NODES) H[(size_t)gr * C1 + n * 16 + lr] = __float2half(acc[n][j]);
        }
#pragma unroll
    for (int j = 0; j < 4; ++j) {
        int gr = row0 + w * 16 + (lane >> 4) * 4 + j;
        if (gr < N_NODES) {
            if (lr < 4) as_n[gr * 4 + lr] = acc[8][j];
            else if (lr < 8) ad_n[gr * 4 + (lr - 4)] = acc[8][j];
        }
    }
}

// ====== MFMA GEMM layer2: [h2 | as2 | ad2] = hrelu @ Wt2e (128-row tile) ======
__global__ __launch_bounds__(512) void gemm2_mfma(const __half* __restrict__ A,
                                                  const _Float16* __restrict__ Wt2e,
                                                  __half* __restrict__ H,
                                                  float* __restrict__ as_n,
                                                  float* __restrict__ ad_n) {
    __shared__ _Float16 Bt[N2E * 136];
    const int tid = threadIdx.x;
    const int w = tid >> 6, lane = tid & 63;
    const int row0 = blockIdx.x * 128;
    const int lr = lane & 15, lk = (lane >> 4) * 8;
    if (tid < 160) {
        int c = tid >> 1, q = tid & 1;
        const h8* wp = (const h8*)(Wt2e + (size_t)c * C1 + q * 64);
#pragma unroll
        for (int j = 0; j < 8; ++j)
            *(h8*)(&Bt[c * 136 + q * 64 + j * 8]) = wp[j];
    }
    __syncthreads();
    f32x4 acc[5];
#pragma unroll
    for (int n = 0; n < 5; ++n) acc[n] = (f32x4){0.f, 0.f, 0.f, 0.f};
    int grow = row0 + w * 16 + lr;
    grow = grow < N_NODES ? grow : N_NODES - 1;
    const _Float16* Ah = (const _Float16*)A;
#pragma unroll
    for (int kk = 0; kk < C1; kk += 32) {
        h8 a = *(const h8*)(Ah + (size_t)grow * C1 + kk + lk);
#pragma unroll
        for (int n = 0; n < 5; ++n) {
            h8 b = *(const h8*)(&Bt[(n * 16 + lr) * 136 + kk + lk]);
            acc[n] = __builtin_amdgcn_mfma_f32_16x16x32_f16(a, b, acc[n], 0, 0, 0);
        }
    }
#pragma unroll
    for (int n = 0; n < 4; ++n)
#pragma unroll
        for (int j = 0; j < 4; ++j) {
            int gr = row0 + w * 16 + (lane >> 4) * 4 + j;
            if (gr < N_NODES) H[(size_t)gr * OUT_CH + n * 16 + lr] = __float2half(acc[n][j]);
        }
#pragma unroll
    for (int j = 0; j < 4; ++j) {
        int gr = row0 + w * 16 + (lane >> 4) * 4 + j;
        if (gr < N_NODES) {
            if (lr == 0) as_n[gr] = acc[4][j];
            else if (lr == 1) ad_n[gr] = acc[4][j];
        }
    }
}

// ================= CSR build =================
// k_bucket: per-WAVE LDS histograms + int4 vector loads (N_EDGES%8==0).
__global__ __launch_bounds__(256) void k_bucket(const int* __restrict__ src,
                                                const int* __restrict__ dst,
                                                int* __restrict__ bcur,
                                                int* __restrict__ pairs) {
    __shared__ int cnt[4 * NBKT];
    __shared__ int base[4 * NBKT];
    const int t = threadIdx.x;
    const int w = t >> 6;
    for (int i = t; i < 4 * NBKT; i += 256) cnt[i] = 0;
    __syncthreads();
    const int e0 = blockIdx.x * 2048 + t * 8;
    int s[8], d[8], r[8];
    bool valid = e0 + 7 < N_EDGES;   // chunks of 8 are all-or-nothing (800000%8==0)
    if (valid) {
        int4 sa = *(const int4*)(src + e0);
        int4 sb = *(const int4*)(src + e0 + 4);
        int4 da = *(const int4*)(dst + e0);
        int4 db = *(const int4*)(dst + e0 + 4);
        s[0] = sa.x; s[1] = sa.y; s[2] = sa.z; s[3] = sa.w;
        s[4] = sb.x; s[5] = sb.y; s[6] = sb.z; s[7] = sb.w;
        d[0] = da.x; d[1] = da.y; d[2] = da.z; d[3] = da.w;
        d[4] = db.x; d[5] = db.y; d[6] = db.z; d[7] = db.w;
#pragma unroll
        for (int k = 0; k < 8; ++k)
            r[k] = atomicAdd(&cnt[w * NBKT + (d[k] >> BSHIFT)], 1);
    }
    __syncthreads();
    if (t < NBKT) {
        int c0 = cnt[0 * NBKT + t], c1 = cnt[1 * NBKT + t];
        int c2 = cnt[2 * NBKT + t], c3 = cnt[3 * NBKT + t];
        int g = atomicAdd(&bcur[t], c0 + c1 + c2 + c3);
        base[0 * NBKT + t] = g;
        base[1 * NBKT + t] = g + c0;
        base[2 * NBKT + t] = g + c0 + c1;
        base[3 * NBKT + t] = g + c0 + c1 + c2;
    }
    __syncthreads();
    if (valid) {
#pragma unroll
        for (int k = 0; k < 8; ++k) {
            int bin = d[k] >> BSHIFT;
            int pos = base[w * NBKT + bin] + r[k];
            if (pos < (bin + 1) * BCAP)      // overflow guard (10-sigma margin)
                pairs[pos] = ((d[k] & 1023) << 16) | s[k];   // src<50000<2^16
        }
    }
}

// k_csr: per-bucket histogram -> LDS scan -> LDS-cursor scatter; int4 passes.
__global__ __launch_bounds__(256) void k_csr(const int* __restrict__ pairs,
                                             const int* __restrict__ bcur,
                                             int* __restrict__ estart,
                                             int* __restrict__ eend,
                                             int* __restrict__ esrc) {
    __shared__ int hist[1024];
    __shared__ int cur[1024];
    __shared__ int s[256];
    const int b = blockIdx.x;
    const int t = threadIdx.x;
#pragma unroll
    for (int k = t; k < 1024; k += 256) hist[k] = 0;
    __syncthreads();
    int cnt = bcur[b] - b * BCAP;
    if (cnt > BCAP) cnt = BCAP;
    const int* p = pairs + (size_t)b * BCAP;
    const int cnt4 = cnt & ~3;
    for (int i = t * 4; i < cnt4; i += 1024) {
        int4 v = *(const int4*)(p + i);
        atomicAdd(&hist[v.x >> 16], 1);
        atomicAdd(&hist[v.y >> 16], 1);
        atomicAdd(&hist[v.z >> 16], 1);
        atomicAdd(&hist[v.w >> 16], 1);
    }
    for (int i = cnt4 + t; i < cnt; i += 256)
        atomicAdd(&hist[p[i] >> 16], 1);
    __syncthreads();
    int h0 = hist[4 * t], h1 = hist[4 * t + 1], h2 = hist[4 * t + 2], h3 = hist[4 * t + 3];
    int sum = h0 + h1 + h2 + h3;
    s[t] = sum;
    __syncthreads();
#pragma unroll
    for (int o = 1; o < 256; o <<= 1) {
        int v = (t >= o) ? s[t - o] : 0;
        __syncthreads();
        s[t] += v;
        __syncthreads();
    }
    int excl = s[t] - sum;
    int gbase = b * BCAP + excl;
    cur[4 * t]     = gbase;
    cur[4 * t + 1] = gbase + h0;
    cur[4 * t + 2] = gbase + h0 + h1;
    cur[4 * t + 3] = gbase + h0 + h1 + h2;
    const int nbase = b << BSHIFT;
#pragma unroll
    for (int i = 0; i < 4; ++i) {
        int node = nbase + 4 * t + i;
        if (node < N_NODES) {
            int st = cur[4 * t + i];
            estart[node] = st;
            eend[node] = st + hist[4 * t + i];
        }
    }
    __syncthreads();
    for (int i = t * 4; i < cnt4; i += 1024) {
        int4 v = *(const int4*)(p + i);
        esrc[atomicAdd(&cur[v.x >> 16], 1)] = v.x & 0xFFFF;
        esrc[atomicAdd(&cur[v.y >> 16], 1)] = v.y & 0xFFFF;
        esrc[atomicAdd(&cur[v.z >> 16], 1)] = v.z & 0xFFFF;
        esrc[atomicAdd(&cur[v.w >> 16], 1)] = v.w & 0xFFFF;
    }
    for (int i = cnt4 + t; i < cnt; i += 256) {
        int v = p[i];
        esrc[atomicAdd(&cur[v >> 16], 1)] = v & 0xFFFF;
    }
}

// ====== aggr1 (measured-optimum): wave per node, 16-lane quarter, 2 slots ======
__global__ __launch_bounds__(256) void gat_aggr1_csr(const int* __restrict__ estart,
                                                     const int* __restrict__ eend,
                                                     const int* __restrict__ esrc,
                                                     const float* __restrict__ as1,
                                                     const float* __restrict__ ad1,
                                                     const __half* __restrict__ h1,
                                                     const float* __restrict__ b1,
                                                     __half* __restrict__ hrelu) {
    int n = blockIdx.x * 4 + (threadIdx.x >> 6);
    if (n >= N_NODES) return;
    const int lane = threadIdx.x & 63;
    const int q = lane >> 4, li = lane & 15;
    const int head = li >> 2;
    const int c0 = li * 8;
    const int base = estart[n];
    const int end = eend[n];
    const float ad = ad1[n * 4 + head];
    const _Float16* __restrict__ H = (const _Float16*)h1;
    float den0 = 0.f, den1 = 0.f;
    float acc0[8], acc1[8];
#pragma unroll
    for (int k = 0; k < 8; ++k) { acc0[k] = 0.f; acc1[k] = 0.f; }

    for (int b0 = base; b0 < end; b0 += 64) {
        int cnt = end - b0; if (cnt > 64) cnt = 64;
        int myidx = (lane < cnt) ? esrc[b0 + lane] : 0;
        for (int it = 0; it < cnt; it += 8) {
            int j0 = it + q * 2, j1 = j0 + 1;
            bool p0 = j0 < cnt, p1 = j1 < cnt;
            int s0 = __shfl(myidx, p0 ? j0 : 0);
            int s1 = __shfl(myidx, p1 ? j1 : 0);
            float x0 = as1[s0 * 4 + head] + ad;
            x0 = x0 > 0.f ? x0 : NEG * x0;
            float w0 = p0 ? exp2f(x0) : 0.f;     // coefs pre-scaled by 1/ln2
            float x1 = as1[s1 * 4 + head] + ad;
            x1 = x1 > 0.f ? x1 : NEG * x1;
            float w1 = p1 ? exp2f(x1) : 0.f;
            h8 hv0 = *(const h8*)(H + (size_t)s0 * C1 + c0);
            h8 hv1 = *(const h8*)(H + (size_t)s1 * C1 + c0);
            den0 += w0;
            den1 += w1;
#pragma unroll
            for (int k = 0; k < 8; ++k) {
                acc0[k] = fmaf((float)hv0[k], w0, acc0[k]);
                acc1[k] = fmaf((float)hv1[k], w1, acc1[k]);
            }
        }
    }
    float den = den0 + den1;
    float r[8];
#pragma unroll
    for (int k = 0; k < 8; ++k) r[k] = acc0[k] + acc1[k];
    den += __shfl_xor(den, 16);
    den += __shfl_xor(den, 32);
#pragma unroll
    for (int k = 0; k < 8; ++k) {
        r[k] += __shfl_xor(r[k], 16);
        r[k] += __shfl_xor(r[k], 32);
    }
    if (q == 0) {
        float4 bb0 = *(const float4*)(b1 + c0);
        float4 bb1 = *(const float4*)(b1 + c0 + 4);
        float bv[8] = {bb0.x, bb0.y, bb0.z, bb0.w, bb1.x, bb1.y, bb1.z, bb1.w};
        float inv = 1.f / (den + 1e-16f);
        h8 o;
#pragma unroll
        for (int k = 0; k < 8; ++k) {
            float v = fmaf(r[k], inv, bv[k]);
            o[k] = (_Float16)(v > 0.f ? v : 0.f);
        }
        *(h8*)((_Float16*)hrelu + (size_t)n * C1 + c0) = o;
    }
}

// ====== aggr2: wave per node, 8-lane group per edge, 2 slots ======
__global__ __launch_bounds__(256) void gat_aggr2_csr(const int* __restrict__ estart,
                                                     const int* __restrict__ eend,
                                                     const int* __restrict__ esrc,
                                                     const float* __restrict__ as2,
                                                     const float* __restrict__ ad2,
                                                     const __half* __restrict__ h2,
                                                     const float* __restrict__ b2,
                                                     float* __restrict__ out) {
    int n = blockIdx.x * 4 + (threadIdx.x >> 6);
    if (n >= N_NODES) return;
    const int lane = threadIdx.x & 63;
    const int q = lane >> 3, li = lane & 7;
    const int c0 = li * 8;
    const int base = estart[n];
    const int end = eend[n];
    const float ad = ad2[n];
    const _Float16* __restrict__ H = (const _Float16*)h2;
    float den0 = 0.f, den1 = 0.f;
    float acc0[8], acc1[8];
#pragma unroll
    for (int k = 0; k < 8; ++k) { acc0[k] = 0.f; acc1[k] = 0.f; }

    for (int b0 = base; b0 < end; b0 += 64) {
        int cnt = end - b0; if (cnt > 64) cnt = 64;
        int myidx = (lane < cnt) ? esrc[b0 + lane] : 0;
        for (int it = 0; it < cnt; it += 16) {
            int j0 = it + q * 2, j1 = j0 + 1;
            bool p0 = j0 < cnt, p1 = j1 < cnt;
            int s0 = __shfl(myidx, p0 ? j0 : 0);
            int s1 = __shfl(myidx, p1 ? j1 : 0);
            float x0 = as2[s0] + ad;
            x0 = x0 > 0.f ? x0 : NEG * x0;
            float w0 = p0 ? exp2f(x0) : 0.f;
            float x1 = as2[s1] + ad;
            x1 = x1 > 0.f ? x1 : NEG * x1;
            float w1 = p1 ? exp2f(x1) : 0.f;
            h8 hv0 = *(const h8*)(H + (size_t)s0 * OUT_CH + c0);
            h8 hv1 = *(const h8*)(H + (size_t)s1 * OUT_CH + c0);
            den0 += w0;
            den1 += w1;
#pragma unroll
            for (int k = 0; k < 8; ++k) {
                acc0[k] = fmaf((float)hv0[k], w0, acc0[k]);
                acc1[k] = fmaf((float)hv1[k], w1, acc1[k]);
            }
        }
    }
    float den = den0 + den1;
    float r[8];
#pragma unroll
    for (int k = 0; k < 8; ++k) r[k] = acc0[k] + acc1[k];
    den += __shfl_xor(den, 8);
    den += __shfl_xor(den, 16);
    den += __shfl_xor(den, 32);
#pragma unroll
    for (int k = 0; k < 8; ++k) {
        r[k] += __shfl_xor(r[k], 8);
        r[k] += __shfl_xor(r[k], 16);
        r[k] += __shfl_xor(r[k], 32);
    }
    if (q == 0) {
        float4 bb0 = *(const float4*)(b2 + c0);
        float4 bb1 = *(const float4*)(b2 + c0 + 4);
        float inv = 1.f / (den + 1e-16f);
        float4 o0, o1;
        o0.x = fmaf(r[0], inv, bb0.x);
        o0.y = fmaf(r[1], inv, bb0.y);
        o0.z = fmaf(r[2], inv, bb0.z);
        o0.w = fmaf(r[3], inv, bb0.w);
        o1.x = fmaf(r[4], inv, bb1.x);
        o1.y = fmaf(r[5], inv, bb1.y);
        o1.z = fmaf(r[6], inv, bb1.z);
        o1.w = fmaf(r[7], inv, bb1.w);
        *(float4*)(out + (size_t)n * OUT_CH + c0) = o0;
        *(float4*)(out + (size_t)n * OUT_CH + c0 + 4) = o1;
    }
}

extern "C" void kernel_launch(void* const* d_in, const int* in_sizes, int n_in,
                              void* d_out, int out_size, void* d_ws, size_t ws_size,
                              hipStream_t stream) {
    const float* x      = (const float*)d_in[0];
    const int*   ei     = (const int*)d_in[1];
    const float* W1     = (const float*)d_in[2];
    const float* a_src1 = (const float*)d_in[3];
    const float* a_dst1 = (const float*)d_in[4];
    const float* b1     = (const float*)d_in[5];
    const float* W2     = (const float*)d_in[6];
    const float* a_src2 = (const float*)d_in[7];
    const float* a_dst2 = (const float*)d_in[8];
    const float* b2     = (const float*)d_in[9];
    float* out = (float*)d_out;

    const int* src = ei;
    const int* dst = ei + N_EDGES;

    char* w = (char*)d_ws;
    auto carve = [&](size_t bytes) {
        char* p = w;
        w += (bytes + 255) & ~(size_t)255;
        return p;
    };
    __half*   h1     = (__half*)carve((size_t)N_NODES * C1 * 2);   // phase2: h2 aliases
    __half*   hrelu  = (__half*)carve((size_t)N_NODES * C1 * 2);
    float*    as1    = (float*)carve((size_t)N_NODES * 4 * 4);     // phase2: as2
    float*    ad1    = (float*)carve((size_t)N_NODES * 4 * 4);     // phase2: ad2
    int*      estart = (int*)carve((size_t)N_NODES * 4);
    int*      eend   = (int*)carve((size_t)N_NODES * 4);
    int*      esrc   = (int*)carve((size_t)NBKT * BCAP * 4);
    int*      bcur   = (int*)carve((size_t)NBKT * 4);
    int*      pairs  = (int*)carve((size_t)NBKT * BCAP * 4);
    _Float16* Wt1e   = (_Float16*)carve((size_t)N1E * IN_CH * 2);
    _Float16* Wt2e   = (_Float16*)carve((size_t)N2E * C1 * 2);

    __half* h2  = h1;
    float*  as2 = as1;
    float*  ad2 = ad1;

    // ---- CSR build + weight prep (3 kernels; shared by both layers) ----
    k_prep<<<184, 256, 0, stream>>>(W1, W2, a_src1, a_dst1, a_src2, a_dst2,
                                    Wt1e, Wt2e, bcur);
    k_bucket<<<(N_EDGES + 2047) / 2048, 256, 0, stream>>>(src, dst, bcur, pairs);
    k_csr<<<NBKT, 256, 0, stream>>>(pairs, bcur, estart, eend, esrc);

    // ---- layer 1 ----
    gemm1_mfma<<<(N_NODES + 127) / 128, 512, 0, stream>>>(x, Wt1e, h1, as1, ad1);
    gat_aggr1_csr<<<(N_NODES + 3) / 4, 256, 0, stream>>>(estart, eend, esrc, as1, ad1, h1, b1, hrelu);

    // ---- layer 2 ----
    gemm2_mfma<<<(N_NODES + 127) / 128, 512, 0, stream>>>(hrelu, Wt2e, h2, as2, ad2);
    gat_aggr2_csr<<<(N_NODES + 3) / 4, 256, 0, stream>>>(estart, eend, esrc, as2, ad2, h2, b2, out);

    (void)in_sizes; (void)n_in; (void)out_size; (void)ws_size;
}